// Round 9
// baseline (18082.536 us; speedup 1.0000x reference)
//
#include <hip/hip_runtime.h>
#include <math.h>

// SCNN lane-detection net on MI355X. Round 9: software-pipelined MFMA conv K-loop.
// R8's loop exposed the full global-load latency between the two barriers of every
// 32-K chunk (load -> vmcnt wait -> ds_write -> barrier -> mfma -> barrier). Now the
// next chunk is prefetched into VGPRs right AFTER the barrier pair, so the mandatory
// vmcnt(0) drain at the NEXT barrier happens one full MFMA-block later: L2 latency
// fully hidden, HBM mostly. Tap & K loops flattened into one pipelined chunk loop.
// All layouts/grids/scans/tail identical to the passing R8.

#define NB 4

typedef unsigned short ushort_t;
typedef __attribute__((ext_vector_type(8))) short short8x;   // 8 bf16 (4 VGPRs)
typedef __attribute__((ext_vector_type(4))) float facc4;     // 4 fp32 acc

static __device__ __forceinline__ ushort_t f2bh(float x) {
    unsigned u = __float_as_uint(x);
    unsigned r = u + 0x7fffu + ((u >> 16) & 1u);
    return (ushort_t)(r >> 16);
}
static __device__ __forceinline__ float bh2f(ushort_t h) {
    return __uint_as_float(((unsigned)h) << 16);
}
static __device__ __forceinline__ void split_store(float v, ushort_t* __restrict__ hi,
                                                   ushort_t* __restrict__ lo, size_t idx) {
    ushort_t h = f2bh(v);
    float l = v - bh2f(h);
    hi[idx] = h;
    lo[idx] = f2bh(l);
}
static __device__ __forceinline__ void ld8f(const float* p, float f[8]) {
    float4 a = *(const float4*)p;
    float4 b = *(const float4*)(p + 4);
    f[0] = a.x; f[1] = a.y; f[2] = a.z; f[3] = a.w;
    f[4] = b.x; f[5] = b.y; f[6] = b.z; f[7] = b.w;
}

// ---------------- fp32 weight transpose [O,IK] -> [IK,O] (conv11 only) ----------------
__global__ __launch_bounds__(256) void repack_w_k(const float* __restrict__ w, float* __restrict__ wre,
                                                  int O, int IK) {
    int gid = blockIdx.x * 256 + threadIdx.x;
    if (gid >= O * IK) return;
    int o = gid / IK;
    int r = gid - o * IK;
    wre[r * O + o] = w[gid];
}

// ---------------- conv11 direct (Cin=3) -> NHWC hi/lo strip T1 [4,20,802,64] ----------------
__global__ __launch_bounds__(256) void conv11_strip_k(const float* __restrict__ X0, const float* __restrict__ W11,
                                                      const float* __restrict__ sc, const float* __restrict__ bi,
                                                      ushort_t* __restrict__ Thi, ushort_t* __restrict__ Tlo, int r0) {
    int gid = blockIdx.x * 256 + threadIdx.x;
    if (gid >= 4 * 20 * 802 * 8) return;
    int c8 = gid & 7;
    int t = gid >> 3;
    int w = t % 802; t /= 802;
    int tr = t % 20;
    int b = t / 20;
    int gr = r0 - 1 + tr;
    int gc = w - 1;
    size_t obase = (((size_t)b * 20 + tr) * 802 + w) * 64 + c8 * 8;
    if (gr < 0 || gr >= 288 || gc < 0 || gc >= 800) {
#pragma unroll
        for (int j = 0; j < 8; ++j) { Thi[obase + j] = 0; Tlo[obase + j] = 0; }
        return;
    }
    float acc[8];
#pragma unroll
    for (int j = 0; j < 8; ++j) acc[j] = 0.f;
#pragma unroll
    for (int ci = 0; ci < 3; ++ci) {
        const float* inc = X0 + (size_t)(b * 3 + ci) * 288 * 800;
#pragma unroll
        for (int kh = 0; kh < 3; ++kh) {
            int ih = gr + kh - 1;
            if (ih < 0 || ih >= 288) continue;
#pragma unroll
            for (int kw = 0; kw < 3; ++kw) {
                int iw = gc + kw - 1;
                if (iw < 0 || iw >= 800) continue;
                float v = inc[ih * 800 + iw];
                float wf[8];
                ld8f(W11 + (ci * 9 + kh * 3 + kw) * 64 + c8 * 8, wf);
#pragma unroll
                for (int j = 0; j < 8; ++j) acc[j] = fmaf(v, wf[j], acc[j]);
            }
        }
    }
#pragma unroll
    for (int j = 0; j < 8; ++j) {
        int n = c8 * 8 + j;
        float r = acc[j] * sc[n] + bi[n];
        r = r > 0.f ? r : 0.f;
        split_store(r, Thi, Tlo, obase + j);
    }
}

// ---------------- MFMA weight repack: [O,I,taps] fp32 -> hi/lo bf16 [t][n][k] ----------------
__global__ __launch_bounds__(256) void repack_wmfma_k(const float* __restrict__ w, ushort_t* __restrict__ whi,
                                                      ushort_t* __restrict__ wlo, int N, int Cin, int taps) {
    int gid = blockIdx.x * 256 + threadIdx.x;
    if (gid >= N * Cin * taps) return;
    int o = gid / (Cin * taps);
    int r = gid - o * Cin * taps;
    int i = r / taps;
    int t = r - i * taps;
    float x = w[gid];
    size_t d = ((size_t)t * N + o) * Cin + i;
    ushort_t h = f2bh(x);
    whi[d] = h;
    wlo[d] = f2bh(x - bh2f(h));
}

// ---------------- generic vertical 2x maxpool on NHWC hi/lo ----------------
__global__ __launch_bounds__(256) void vpool2_k(const ushort_t* __restrict__ shi, const ushort_t* __restrict__ slo,
                                                ushort_t* __restrict__ dhi, ushort_t* __restrict__ dlo,
                                                int Hs, int Wp, int C, int Hop, int Wop, int pad, int pr0) {
    int total = 4 * (Hs >> 1) * Wp * C;
    int gid = blockIdx.x * 256 + threadIdx.x;
    if (gid >= total) return;
    int c = gid % C;
    int t = gid / C;
    int w = t % Wp; t /= Wp;
    int hp = t % (Hs >> 1);
    int b = t / (Hs >> 1);
    size_t a0 = (((size_t)b * Hs + 2 * hp) * Wp + w) * C + c;
    size_t a1 = a0 + (size_t)Wp * C;
    float v0 = bh2f(shi[a0]) + bh2f(slo[a0]);
    float v1 = bh2f(shi[a1]) + bh2f(slo[a1]);
    float v = fmaxf(v0, v1);
    size_t d = (((size_t)b * Hop + pr0 + hp + pad) * Wop + (w + pad)) * C + c;
    split_store(v, dhi, dlo, d);
}

// ---------------- generic MFMA conv (split-bf16 hi/lo, 3-MFMA), software-pipelined ----------------
// Block tile 128 x (NJ*32). NJ=4: waves compute 64x64. NJ=2: 64x32 (conv12).
// MODE 0: NHWC padded hi/lo out. MODE 1: +horizontal maxpool. MODE 2: NCHW fp32 out.
template <int MODE, int NJ>
__global__ __launch_bounds__(256) void mfma_conv_k(
    const ushort_t* __restrict__ Ahi, const ushort_t* __restrict__ Alo,
    const ushort_t* __restrict__ Whi, const ushort_t* __restrict__ Wlo,
    const float* __restrict__ sc, const float* __restrict__ bi,
    ushort_t* __restrict__ Ohi, ushort_t* __restrict__ Olo, float* __restrict__ Fo,
    int M, int Wimg, int HS, int h0,
    int HpIn, int WpIn, int Cin, int ih0, int iph, int ipw, int dil, int taps,
    int N, int obst, int oh0, int oph, int opw, int WpOut) {
    constexpr int NT = NJ * 32;
    __shared__ ushort_t sA0[128 * 40], sA1[128 * 40];
    __shared__ ushort_t sB0[NT * 40], sB1[NT * 40];

    int tid = threadIdx.x;
    int m0 = blockIdx.x * 128;
    int n0 = blockIdx.y * NT;

    int ar = tid >> 1;
    int ah = (tid & 1) * 16;
    int am = m0 + ar;
    if (am >= M) am = M - 1;
    int aw = am % Wimg;
    int t1 = am / Wimg;
    int ahh = h0 + t1 % HS;
    int ab = t1 / HS;

    int br, bhh, bpl;
    if (NJ == 4) {
        br = tid >> 1; bhh = (tid & 1) * 16; bpl = 2;
    } else {
        int bp = tid >> 7;
        int bidx = tid & 127;
        br = bidx >> 1; bhh = (bidx & 1) * 16; bpl = bp;
    }

    int wid = tid >> 6, lane = tid & 63;
    int moff = (wid >> 1) * 64;
    int noff = (wid & 1) * (NJ * 16);
    int lm = lane & 15, quad = lane >> 4;

    facc4 acc[4][NJ];
#pragma unroll
    for (int i = 0; i < 4; ++i)
#pragma unroll
        for (int j = 0; j < NJ; ++j) acc[i][j] = (facc4)(0.f);

    const long abase = ((long)ab * HpIn + (ahh - ih0 + iph)) * WpIn + (aw + ipw);
    const long bbase = (long)(n0 + br) * Cin + bhh;
    const int nch = Cin >> 5;
    const int total = taps * nch;

    uint4 rA[4];
    uint4 rB[4];

    auto issue_loads = [&](int t, int k0) {
        int dh = 0, dw = 0;
        if (taps == 9) {
            dh = (t / 3 - 1) * dil;
            dw = (t % 3 - 1) * dil;
        }
        long ao = (abase + (long)dh * WpIn + dw) * Cin + ah + k0;
        const ushort_t* p = Ahi + ao;
        rA[0] = *(const uint4*)p;
        rA[1] = *(const uint4*)(p + 8);
        const ushort_t* q = Alo + ao;
        rA[2] = *(const uint4*)q;
        rA[3] = *(const uint4*)(q + 8);
        long bo = (long)t * N * Cin + bbase + k0;
        if (NJ == 4) {
            const ushort_t* pb = Whi + bo;
            rB[0] = *(const uint4*)pb;
            rB[1] = *(const uint4*)(pb + 8);
            const ushort_t* qb = Wlo + bo;
            rB[2] = *(const uint4*)qb;
            rB[3] = *(const uint4*)(qb + 8);
        } else {
            const ushort_t* pb = (bpl ? Wlo : Whi) + bo;
            rB[0] = *(const uint4*)pb;
            rB[1] = *(const uint4*)(pb + 8);
        }
    };

    issue_loads(0, 0);
    int tn = 0, kn = 0;
    for (int i = 0; i < total; ++i) {
        ++kn;
        if (kn == nch) { kn = 0; ++tn; }
        __syncthreads();  // drains prefetch i (latency was covered by MFMA of i-1)
        *(uint4*)&sA0[ar * 40 + ah] = rA[0];
        *(uint4*)&sA0[ar * 40 + ah + 8] = rA[1];
        *(uint4*)&sA1[ar * 40 + ah] = rA[2];
        *(uint4*)&sA1[ar * 40 + ah + 8] = rA[3];
        if (NJ == 4) {
            *(uint4*)&sB0[br * 40 + bhh] = rB[0];
            *(uint4*)&sB0[br * 40 + bhh + 8] = rB[1];
            *(uint4*)&sB1[br * 40 + bhh] = rB[2];
            *(uint4*)&sB1[br * 40 + bhh + 8] = rB[3];
        } else {
            ushort_t* dst = bpl ? sB1 : sB0;
            *(uint4*)&dst[br * 40 + bhh] = rB[0];
            *(uint4*)&dst[br * 40 + bhh + 8] = rB[1];
        }
        __syncthreads();
        if (i + 1 < total) issue_loads(tn, kn * 32);  // prefetch i+1; covered by MFMAs below
        short8x afh[4], afl[4], bfh[NJ], bfl[NJ];
#pragma unroll
        for (int mi = 0; mi < 4; ++mi) {
            int base = (moff + mi * 16 + lm) * 40 + quad * 8;
            afh[mi] = *(const short8x*)&sA0[base];
            afl[mi] = *(const short8x*)&sA1[base];
        }
#pragma unroll
        for (int nj = 0; nj < NJ; ++nj) {
            int base = (noff + nj * 16 + lm) * 40 + quad * 8;
            bfh[nj] = *(const short8x*)&sB0[base];
            bfl[nj] = *(const short8x*)&sB1[base];
        }
#pragma unroll
        for (int mi = 0; mi < 4; ++mi)
#pragma unroll
            for (int nj = 0; nj < NJ; ++nj) {
                acc[mi][nj] = __builtin_amdgcn_mfma_f32_16x16x32_bf16(afh[mi], bfh[nj], acc[mi][nj], 0, 0, 0);
                acc[mi][nj] = __builtin_amdgcn_mfma_f32_16x16x32_bf16(afl[mi], bfh[nj], acc[mi][nj], 0, 0, 0);
                acc[mi][nj] = __builtin_amdgcn_mfma_f32_16x16x32_bf16(afh[mi], bfl[nj], acc[mi][nj], 0, 0, 0);
            }
    }

#pragma unroll
    for (int mi = 0; mi < 4; ++mi)
#pragma unroll
        for (int nj = 0; nj < NJ; ++nj) {
            int nglob = n0 + noff + nj * 16 + lm;
            float s = sc[nglob];
            float bb = bi[nglob];
            if (MODE == 1) {
#pragma unroll
                for (int rg = 0; rg < 4; rg += 2) {
                    int mg = m0 + moff + mi * 16 + quad * 4 + rg;
                    if (mg >= M) continue;
                    float v0 = acc[mi][nj][rg] * s + bb;
                    v0 = v0 > 0.f ? v0 : 0.f;
                    float v1 = acc[mi][nj][rg + 1] * s + bb;
                    v1 = v1 > 0.f ? v1 : 0.f;
                    float v = fmaxf(v0, v1);
                    int wq = mg % Wimg;
                    int tq = mg / Wimg;
                    int hq = h0 + tq % HS;
                    int bq = tq / HS;
                    size_t a = ((size_t)bq * obst + (size_t)(hq - oh0) * WpOut + (wq >> 1)) * N + nglob;
                    split_store(v, Ohi, Olo, a);
                }
            } else {
#pragma unroll
                for (int rg = 0; rg < 4; ++rg) {
                    int mg = m0 + moff + mi * 16 + quad * 4 + rg;
                    if (mg >= M) continue;
                    float v = acc[mi][nj][rg] * s + bb;
                    v = v > 0.f ? v : 0.f;
                    int wq = mg % Wimg;
                    int tq = mg / Wimg;
                    int hq = h0 + tq % HS;
                    int bq = tq / HS;
                    if (MODE == 0) {
                        size_t a = ((size_t)bq * obst + (size_t)(hq - oh0 + oph) * WpOut + (wq + opw)) * N + nglob;
                        split_store(v, Ohi, Olo, a);
                    } else {
                        size_t a = (((size_t)bq * N + nglob) * HS + (hq - h0)) * Wimg + wq;
                        Fo[a] = v;
                    }
                }
            }
        }
}

// ========================= scans + tail (proven) =========================
__global__ __launch_bounds__(256) void repack_scan_k(const float* __restrict__ w, float* __restrict__ wre) {
    int gid = blockIdx.x * 256 + threadIdx.x;
    if (gid >= 128 * 128 * 9) return;
    int o = gid / 1152;
    int r = gid - o * 1152;
    wre[r * 128 + o] = w[gid];
}

__global__ __launch_bounds__(256) void scan_row_k(float* __restrict__ F, const float* __restrict__ wsc, int hp, int hc) {
    __shared__ float sm[128 * 12];
    int b = blockIdx.x / 25;
    int w0 = (blockIdx.x % 25) * 4;
    int tid = threadIdx.x;
    const float* Fp = F + ((size_t)(b * 128) * 36 + hp) * 100;
    for (int i = tid; i < 1536; i += 256) {
        int ci = i / 12;
        int j = i - ci * 12;
        int iw = w0 - 4 + j;
        sm[i] = (iw >= 0 && iw < 100) ? Fp[(size_t)ci * 3600 + iw] : 0.f;
    }
    __syncthreads();
    int o = tid & 127;
    int half = tid >> 7;
    float a0 = 0.f, a1 = 0.f;
    for (int ci = 0; ci < 128; ++ci) {
        const float* s = sm + ci * 12 + half * 2;
        const float* wp = wsc + ci * 9 * 128 + o;
#pragma unroll
        for (int k = 0; k < 9; ++k) {
            float wt = wp[k * 128];
            a0 = fmaf(s[k], wt, a0);
            a1 = fmaf(s[k + 1], wt, a1);
        }
    }
    int w = w0 + half * 2;
    float* outp = F + ((size_t)(b * 128 + o) * 36 + hc) * 100 + w;
    outp[0] += a0 > 0.f ? a0 : 0.f;
    outp[1] += a1 > 0.f ? a1 : 0.f;
}

// column scan on transposed FT [4,128,100,36] (h contiguous): coalesced staging
__global__ __launch_bounds__(256) void scan_colT_k(float* __restrict__ FT, const float* __restrict__ wsc, int wp_, int wc) {
    __shared__ float sm[128 * 12];
    int b = blockIdx.x / 9;
    int h0 = (blockIdx.x % 9) * 4;
    int tid = threadIdx.x;
    const float* Fp = FT + (size_t)(b * 128) * 3600 + (size_t)wp_ * 36;
    for (int i = tid; i < 1536; i += 256) {
        int ci = i / 12;
        int j = i - ci * 12;
        int ih = h0 - 4 + j;
        sm[i] = (ih >= 0 && ih < 36) ? Fp[(size_t)ci * 3600 + ih] : 0.f;
    }
    __syncthreads();
    int o = tid & 127;
    int half = tid >> 7;
    float a0 = 0.f, a1 = 0.f;
    for (int ci = 0; ci < 128; ++ci) {
        const float* s = sm + ci * 12 + half * 2;
        const float* wp = wsc + ci * 9 * 128 + o;
#pragma unroll
        for (int k = 0; k < 9; ++k) {
            float wt = wp[k * 128];
            a0 = fmaf(s[k], wt, a0);
            a1 = fmaf(s[k + 1], wt, a1);
        }
    }
    int h = h0 + half * 2;
    float* outp = FT + ((size_t)(b * 128 + o) * 100 + wc) * 36 + h;
    outp[0] += a0 > 0.f ? a0 : 0.f;
    outp[1] += a1 > 0.f ? a1 : 0.f;
}

// F [4,128,36,100] -> FT [4,128,100,36] (coalesced writes)
__global__ __launch_bounds__(256) void transpose_fwd_k(const float* __restrict__ F, float* __restrict__ FT) {
    int gid = blockIdx.x * 256 + threadIdx.x;
    if (gid >= 4 * 128 * 3600) return;
    int h = gid % 36;
    int t = gid / 36;
    int w = t % 100;
    int bc = t / 100;
    FT[gid] = F[(size_t)bc * 3600 + h * 100 + w];
}
// FT -> F (coalesced writes)
__global__ __launch_bounds__(256) void transpose_bwd_k(const float* __restrict__ FT, float* __restrict__ F) {
    int gid = blockIdx.x * 256 + threadIdx.x;
    if (gid >= 4 * 128 * 3600) return;
    int w = gid % 100;
    int t = gid / 100;
    int h = t % 36;
    int bc = t / 36;
    F[gid] = FT[(size_t)bc * 3600 + w * 36 + h];
}

__global__ __launch_bounds__(256) void conv8_k(const float* __restrict__ F, const float* __restrict__ w8,
                                               const float* __restrict__ b8, float* __restrict__ G) {
    int gid = blockIdx.x * 256 + threadIdx.x;
    if (gid >= NB * 3600) return;
    int hw = gid % 3600;
    int b = gid / 3600;
    float acc[5];
#pragma unroll
    for (int c = 0; c < 5; ++c) acc[c] = b8[c];
    const float* Fb = F + (size_t)b * 128 * 3600 + hw;
    for (int ci = 0; ci < 128; ++ci) {
        float v = Fb[(size_t)ci * 3600];
#pragma unroll
        for (int c = 0; c < 5; ++c) acc[c] = fmaf(v, w8[c * 128 + ci], acc[c]);
    }
#pragma unroll
    for (int c = 0; c < 5; ++c) G[(size_t)(b * 5 + c) * 3600 + hw] = acc[c];
}

__global__ __launch_bounds__(256) void resize_softmax_k(const float* __restrict__ G, float* __restrict__ out) {
    int gid = blockIdx.x * 256 + threadIdx.x;
    if (gid >= NB * 288 * 800) return;
    int ox = gid % 800;
    int t = gid / 800;
    int oy = t % 288;
    int b = t / 288;
    float fy = oy * (35.0f / 287.0f);
    int y0 = (int)fy; if (y0 > 34) y0 = 34;
    int y1 = y0 + 1;
    float wy = fy - y0;
    float fx = ox * (99.0f / 799.0f);
    int x0 = (int)fx; if (x0 > 98) x0 = 98;
    int x1 = x0 + 1;
    float wx = fx - x0;
    const float* Gb = G + (size_t)b * 5 * 3600;
    float v[5];
    float m = -1e30f;
#pragma unroll
    for (int c = 0; c < 5; ++c) {
        const float* Gc = Gb + (size_t)c * 3600;
        float a = Gc[y0 * 100 + x0] * (1.f - wx) + Gc[y0 * 100 + x1] * wx;
        float bb = Gc[y1 * 100 + x0] * (1.f - wx) + Gc[y1 * 100 + x1] * wx;
        v[c] = a * (1.f - wy) + bb * wy;
        m = fmaxf(m, v[c]);
    }
    float sum = 0.f;
#pragma unroll
    for (int c = 0; c < 5; ++c) { v[c] = expf(v[c] - m); sum += v[c]; }
    float inv = 1.f / sum;
#pragma unroll
    for (int c = 0; c < 5; ++c) out[((size_t)(b * 5 + c) * 288 + oy) * 800 + ox] = v[c] * inv;
}

__global__ __launch_bounds__(256) void pool_softmax_k(const float* __restrict__ G, float* __restrict__ P) {
    int gid = blockIdx.x * 256 + threadIdx.x;
    if (gid >= NB * 18 * 50) return;
    int pw = gid % 50;
    int t = gid / 50;
    int ph = t % 18;
    int b = t / 18;
    float s5[5] = {0.f, 0.f, 0.f, 0.f, 0.f};
    const float* Gb = G + (size_t)b * 5 * 3600;
#pragma unroll
    for (int dy = 0; dy < 2; ++dy) {
#pragma unroll
        for (int dx = 0; dx < 2; ++dx) {
            int hw = (2 * ph + dy) * 100 + (2 * pw + dx);
            float v[5], m = -1e30f, sum = 0.f;
#pragma unroll
            for (int c = 0; c < 5; ++c) { v[c] = Gb[(size_t)c * 3600 + hw]; m = fmaxf(m, v[c]); }
#pragma unroll
            for (int c = 0; c < 5; ++c) { v[c] = expf(v[c] - m); sum += v[c]; }
            float inv = 1.f / sum;
#pragma unroll
            for (int c = 0; c < 5; ++c) s5[c] += v[c] * inv;
        }
    }
#pragma unroll
    for (int c = 0; c < 5; ++c) P[b * 4500 + c * 900 + ph * 50 + pw] = s5[c] * 0.25f;
}

__global__ __launch_bounds__(256) void fc1_k(const float* __restrict__ P, const float* __restrict__ fw9,
                                             const float* __restrict__ fb9, float* __restrict__ H1) {
    int wid = blockIdx.x * 4 + (threadIdx.x >> 6);
    int lane = threadIdx.x & 63;
    if (wid >= 512) return;
    int b = wid >> 7;
    int o = wid & 127;
    const float* wr = fw9 + (size_t)o * 4500;
    const float* pr = P + b * 4500;
    float acc = 0.f;
    for (int i = lane; i < 4500; i += 64) acc = fmaf(wr[i], pr[i], acc);
    for (int s = 32; s > 0; s >>= 1) acc += __shfl_down(acc, s, 64);
    if (lane == 0) {
        float r = acc + fb9[o];
        H1[b * 128 + o] = r > 0.f ? r : 0.f;
    }
}

__global__ __launch_bounds__(64) void fc2_k(const float* __restrict__ H1, const float* __restrict__ fw10,
                                            const float* __restrict__ fb10, float* __restrict__ dout) {
    int t = threadIdx.x;
    if (t >= 16) return;
    int b = t >> 2;
    int o = t & 3;
    float acc = fb10[o];
    for (int i = 0; i < 128; ++i) acc = fmaf(H1[b * 128 + i], fw10[o * 128 + i], acc);
    dout[4608000 + t] = 1.f / (1.f + expf(-acc));
}

// ======================================================================================
static inline int ceildiv(int a, int b) { return (a + b - 1) / b; }

extern "C" void kernel_launch(void* const* d_in, const int* in_sizes, int n_in,
                              void* d_out, int out_size, void* d_ws, size_t ws_size,
                              hipStream_t stream) {
    (void)in_sizes; (void)n_in; (void)out_size; (void)ws_size;
    char* U = (char*)d_ws;                 // 19,000,064 B utility region
    char* V = U + 19000064;                // 103,424,000 B activation arena

    // ---- U lifetimes ----
    float* W11f = (float*)(U);                       // 6912 B
    ushort_t* WM12 = (ushort_t*)(U + 8192);          // 9*64*64/plane
    ushort_t* WM21 = (ushort_t*)(U + 155648);        // 9*128*64/plane
    ushort_t* WM22 = (ushort_t*)(U + 450560);        // 9*128*128/plane
    ushort_t* T1hi = (ushort_t*)(U + 1050624);       // [4,20,802,64] 8,212,480 B/plane
    ushort_t* T1lo = (ushort_t*)(U + 1050624 + 8212480);
    ushort_t* T3hi = (ushort_t*)(U + 1050624);       // [4,20,402,128] 8,232,960 B/plane
    ushort_t* T3lo = (ushort_t*)(U + 1050624 + 8232960);
    ushort_t* WMa = (ushort_t*)(U);
    ushort_t* WMb = (ushort_t*)(U + 4718592);
    float* WSC = (float*)(U);
    float* G = (float*)(U + 2359296);
    float* P = (float*)(U + 2647296);
    float* H1 = (float*)(U + 2719296);

    // ---- V lifetimes ----
    ushort_t* Xhi = (ushort_t*)(V);                  // [4,74,202,128] pad(1)
    ushort_t* Xlo = (ushort_t*)(V + 15306752);
    ushort_t* S1hi = (ushort_t*)(V + 30613504);      // [4,146,402,64] pad(1) 30,050,304 B/plane
    ushort_t* S1lo = (ushort_t*)(V + 60663808);
    ushort_t* T2hi = (ushort_t*)(V + 90714112);      // 3,686,400 B/plane
    ushort_t* T2lo = (ushort_t*)(V + 90714112 + 3686400);
    ushort_t* Yhi = (ushort_t*)(V + 30613504);       // conv31 out [4,74,202,256]
    ushort_t* Ylo = (ushort_t*)(V + 61227008);
    ushort_t* Zhi = (ushort_t*)(V + 91840512);       // conv32 strip
    ushort_t* Zlo = (ushort_t*)(V + 97632256);
    ushort_t* HPhi = (ushort_t*)(V);                 // conv33+hpool out [4,72,100,256]
    ushort_t* HPlo = (ushort_t*)(V + 14745600);
    ushort_t* PAhi = (ushort_t*)(V + 30613504);      // pooled stage3 [4,44,108,256] pad(4)
    ushort_t* PAlo = (ushort_t*)(V + 40345600);
    ushort_t* SBhi = (ushort_t*)(V + 50077696);      // 512ch slotB [4,44,108,512]
    ushort_t* SBlo = (ushort_t*)(V + 69541888);
    ushort_t* SAhi = (ushort_t*)(V);                 // 512ch slotA
    ushort_t* SAlo = (ushort_t*)(V + 19464192);
    ushort_t* C6hi = (ushort_t*)(V + 38928384);      // conv6 out [4,36,100,1024]
    ushort_t* C6lo = (ushort_t*)(V + 68419584);
    float* F = (float*)(V);                          // SCNN state fp32 NCHW [0, 7,372,800)
    float* FT = (float*)(V + 7372800);               // transposed state [7.37M, 14.75M)

    const float* X0 = (const float*)d_in[0];
    auto din = [&](int i) { return (const float*)d_in[i]; };
    auto wm_lo = [&](ushort_t* base, int taps, int N, int C) { return base + (size_t)taps * N * C; };

    // ================= stage1 =================
    repack_w_k<<<ceildiv(27 * 64, 256), 256, 0, stream>>>(din(1), W11f, 64, 27);
    repack_wmfma_k<<<ceildiv(64 * 64 * 9, 256), 256, 0, stream>>>(din(4), WM12, wm_lo(WM12, 9, 64, 64), 64, 64, 9);
    hipMemsetAsync(V + 30613504, 0, 60100608, stream);  // S1 padding
    for (int s = 0; s < 16; ++s) {
        int r0 = s * 18;
        conv11_strip_k<<<2005, 256, 0, stream>>>(X0, W11f, din(2), din(3), T1hi, T1lo, r0);
        mfma_conv_k<1, 2><<<dim3(450, 1), 256, 0, stream>>>(
            T1hi, T1lo, WM12, wm_lo(WM12, 9, 64, 64), din(5), din(6), T2hi, T2lo, nullptr,
            57600, 800, 18, r0, 20, 802, 64, r0, 1, 1, 1, 9, 64, 18 * 400, r0, 0, 0, 400);
        vpool2_k<<<ceildiv(4 * 9 * 400 * 64, 256), 256, 0, stream>>>(
            T2hi, T2lo, S1hi, S1lo, 18, 400, 64, 146, 402, 1, r0 / 2);
    }
    // ================= stage2 =================
    repack_wmfma_k<<<ceildiv(128 * 64 * 9, 256), 256, 0, stream>>>(din(7), WM21, wm_lo(WM21, 9, 128, 64), 128, 64, 9);
    repack_wmfma_k<<<ceildiv(128 * 128 * 9, 256), 256, 0, stream>>>(din(10), WM22, wm_lo(WM22, 9, 128, 128), 128, 128, 9);
    hipMemsetAsync(V, 0, 30613504, stream);  // X padding
    for (int s = 0; s < 8; ++s) {
        int r0 = s * 18;
        int hstart = r0 - 1 < 0 ? 0 : r0 - 1;
        int hend = r0 + 19 > 144 ? 144 : r0 + 19;
        int rows = hend - hstart;
        int M21 = 4 * rows * 400;
        hipMemsetAsync(U + 1050624, 0, 16465920, stream);  // T3 both planes
        mfma_conv_k<0, 4><<<dim3(ceildiv(M21, 128), 1), 256, 0, stream>>>(
            S1hi, S1lo, WM21, wm_lo(WM21, 9, 128, 64), din(8), din(9), T3hi, T3lo, nullptr,
            M21, 400, rows, hstart, 146, 402, 64, 0, 1, 1, 1, 9, 128, 20 * 402, r0 - 1, 0, 1, 402);
        mfma_conv_k<1, 4><<<dim3(225, 1), 256, 0, stream>>>(
            T3hi, T3lo, WM22, wm_lo(WM22, 9, 128, 128), din(11), din(12), T2hi, T2lo, nullptr,
            28800, 400, 18, r0, 20, 402, 128, r0 - 1, 0, 1, 1, 9, 128, 18 * 200, r0, 0, 0, 200);
        vpool2_k<<<ceildiv(4 * 9 * 200 * 128, 256), 256, 0, stream>>>(
            T2hi, T2lo, Xhi, Xlo, 18, 200, 128, 74, 202, 1, r0 / 2);
    }

    // ================= conv31 =================
    repack_wmfma_k<<<ceildiv(256 * 128 * 9, 256), 256, 0, stream>>>(din(13), WMa, wm_lo(WMa, 9, 256, 128), 256, 128, 9);
    hipMemsetAsync(V + 30613504, 0, 61227008, stream);
    mfma_conv_k<0, 4><<<dim3(450, 2), 256, 0, stream>>>(
        Xhi, Xlo, WMa, wm_lo(WMa, 9, 256, 128), din(14), din(15), Yhi, Ylo, nullptr,
        57600, 200, 72, 0, 74, 202, 128, 0, 1, 1, 1, 9, 256, 74 * 202, 0, 1, 1, 202);
    // ================= conv32/conv33+hpool strips =================
    repack_wmfma_k<<<ceildiv(256 * 256 * 9, 256), 256, 0, stream>>>(din(16), WMa, wm_lo(WMa, 9, 256, 256), 256, 256, 9);
    repack_wmfma_k<<<ceildiv(256 * 256 * 9, 256), 256, 0, stream>>>(din(19), WMb, wm_lo(WMb, 9, 256, 256), 256, 256, 9);
    for (int s = 0; s < 6; ++s) {
        int h0s = s * 12;
        int hstart = h0s - 1 < 0 ? 0 : h0s - 1;
        int hend = h0s + 13 > 72 ? 72 : h0s + 13;
        int rows = hend - hstart;
        int M32 = 4 * rows * 200;
        hipMemsetAsync(V + 91840512, 0, 11583488, stream);
        mfma_conv_k<0, 4><<<dim3(ceildiv(M32, 128), 2), 256, 0, stream>>>(
            Yhi, Ylo, WMa, wm_lo(WMa, 9, 256, 256), din(17), din(18), Zhi, Zlo, nullptr,
            M32, 200, rows, hstart, 74, 202, 256, 0, 1, 1, 1, 9, 256, 14 * 202, h0s - 1, 0, 1, 202);
        mfma_conv_k<1, 4><<<dim3(75, 2), 256, 0, stream>>>(
            Zhi, Zlo, WMb, wm_lo(WMb, 9, 256, 256), din(20), din(21), HPhi, HPlo, nullptr,
            9600, 200, 12, h0s, 14, 202, 256, h0s - 1, 0, 1, 1, 9, 256, 72 * 100, 0, 0, 0, 100);
    }
    hipMemsetAsync(V + 30613504, 0, 19464192, stream);
    vpool2_k<<<ceildiv(4 * 36 * 100 * 256, 256), 256, 0, stream>>>(
        HPhi, HPlo, PAhi, PAlo, 72, 100, 256, 44, 108, 4, 0);

    // ================= conv41..conv53 =================
    struct L { int wi, si, bi, dil; };
    static const L l45[5] = {{25, 26, 27, 1}, {28, 29, 30, 1}, {31, 32, 33, 2}, {34, 35, 36, 2}, {37, 38, 39, 2}};
    repack_wmfma_k<<<ceildiv(512 * 256 * 9, 256), 256, 0, stream>>>(din(22), WMa, wm_lo(WMa, 9, 512, 256), 512, 256, 9);
    hipMemsetAsync(V + 50077696, 0, 38928384, stream);
    mfma_conv_k<0, 4><<<dim3(113, 4), 256, 0, stream>>>(
        PAhi, PAlo, WMa, wm_lo(WMa, 9, 512, 256), din(23), din(24), SBhi, SBlo, nullptr,
        14400, 100, 36, 0, 44, 108, 256, 0, 4, 4, 1, 9, 512, 44 * 108, 0, 4, 4, 108);
    hipMemsetAsync(V, 0, 38928384, stream);  // slotA borders
    for (int i = 0; i < 5; ++i) {
        const L& L0 = l45[i];
        repack_wmfma_k<<<ceildiv(512 * 512 * 9, 256), 256, 0, stream>>>(din(L0.wi), WMa, wm_lo(WMa, 9, 512, 512), 512, 512, 9);
        const ushort_t* ih = (i & 1) ? SAhi : SBhi;
        const ushort_t* il = (i & 1) ? SAlo : SBlo;
        ushort_t* oh = (i & 1) ? SBhi : SAhi;
        ushort_t* ol = (i & 1) ? SBlo : SAlo;
        mfma_conv_k<0, 4><<<dim3(113, 4), 256, 0, stream>>>(
            ih, il, WMa, wm_lo(WMa, 9, 512, 512), din(L0.si), din(L0.bi), oh, ol, nullptr,
            14400, 100, 36, 0, 44, 108, 512, 0, 4, 4, L0.dil, 9, 512, 44 * 108, 0, 4, 4, 108);
    }
    repack_wmfma_k<<<ceildiv(1024 * 512 * 9, 256), 256, 0, stream>>>(din(40), WMa, wm_lo(WMa, 9, 1024, 512), 1024, 512, 9);
    mfma_conv_k<0, 4><<<dim3(113, 8), 256, 0, stream>>>(
        SAhi, SAlo, WMa, wm_lo(WMa, 9, 1024, 512), din(41), din(42), C6hi, C6lo, nullptr,
        14400, 100, 36, 0, 44, 108, 512, 0, 4, 4, 4, 9, 1024, 3600, 0, 0, 0, 100);
    repack_wmfma_k<<<ceildiv(128 * 1024, 256), 256, 0, stream>>>(din(43), WMa, wm_lo(WMa, 1, 128, 1024), 128, 1024, 1);
    mfma_conv_k<2, 4><<<dim3(113, 1), 256, 0, stream>>>(
        C6hi, C6lo, WMa, wm_lo(WMa, 1, 128, 1024), din(44), din(45), nullptr, nullptr, F,
        14400, 100, 36, 0, 36, 100, 1024, 0, 0, 0, 1, 1, 128, 0, 0, 0, 0, 0);

    // ================= SCNN scans + tail =================
    for (int j = 0; j < 4; ++j)
        repack_scan_k<<<576, 256, 0, stream>>>(din(46 + j), WSC + (size_t)j * 147456);
    for (int h = 1; h <= 35; ++h)
        scan_row_k<<<100, 256, 0, stream>>>(F, WSC + 0 * 147456, h - 1, h);
    for (int h = 34; h >= 1; --h)
        scan_row_k<<<100, 256, 0, stream>>>(F, WSC + 1 * 147456, h + 1, h);
    transpose_fwd_k<<<7200, 256, 0, stream>>>(F, FT);
    for (int w = 1; w <= 99; ++w)
        scan_colT_k<<<36, 256, 0, stream>>>(FT, WSC + 2 * (size_t)147456, w - 1, w);
    for (int w = 98; w >= 1; --w)
        scan_colT_k<<<36, 256, 0, stream>>>(FT, WSC + 3 * (size_t)147456, w + 1, w);
    transpose_bwd_k<<<7200, 256, 0, stream>>>(FT, F);

    conv8_k<<<ceildiv(NB * 3600, 256), 256, 0, stream>>>(F, din(50), din(51), G);
    resize_softmax_k<<<ceildiv(NB * 288 * 800, 256), 256, 0, stream>>>(G, (float*)d_out);
    pool_softmax_k<<<ceildiv(NB * 18 * 50, 256), 256, 0, stream>>>(G, P);
    fc1_k<<<128, 256, 0, stream>>>(P, din(52), din(53), H1);
    fc2_k<<<1, 64, 0, stream>>>(H1, din(54), din(55), (float*)d_out);
}

// Round 10
// 10495.979 us; speedup vs baseline: 1.7228x; 1.7228x over previous
//
#include <hip/hip_runtime.h>
#include <math.h>

// SCNN lane-detection net on MI355X. Round 10: R8 base (R9's register prefetch
// reverted — it regressed 11->18 ms via VGPR pressure + defeated compiler
// scheduling). New: MFMA conv staging via __builtin_amdgcn_global_load_lds
// (width=16), per-wave role split (A-hi/A-lo/B-hi/B-lo), fetch-side bank
// swizzle so the contiguous LDS layout reads conflict-equal to the padded one.
// Removes all ds_writes + staging VGPRs from the K-loop (guide mistake #1;
// m93->m97 = 1.69x). Everything else byte-identical to the passing R8.

#define NB 4

typedef unsigned short ushort_t;
typedef __attribute__((ext_vector_type(8))) short short8x;   // 8 bf16 (4 VGPRs)
typedef __attribute__((ext_vector_type(4))) float facc4;     // 4 fp32 acc

static __device__ __forceinline__ ushort_t f2bh(float x) {
    unsigned u = __float_as_uint(x);
    unsigned r = u + 0x7fffu + ((u >> 16) & 1u);
    return (ushort_t)(r >> 16);
}
static __device__ __forceinline__ float bh2f(ushort_t h) {
    return __uint_as_float(((unsigned)h) << 16);
}
static __device__ __forceinline__ void split_store(float v, ushort_t* __restrict__ hi,
                                                   ushort_t* __restrict__ lo, size_t idx) {
    ushort_t h = f2bh(v);
    float l = v - bh2f(h);
    hi[idx] = h;
    lo[idx] = f2bh(l);
}
static __device__ __forceinline__ void ld8f(const float* p, float f[8]) {
    float4 a = *(const float4*)p;
    float4 b = *(const float4*)(p + 4);
    f[0] = a.x; f[1] = a.y; f[2] = a.z; f[3] = a.w;
    f[4] = b.x; f[5] = b.y; f[6] = b.z; f[7] = b.w;
}
// async global->LDS, 16 B per lane; LDS dst = wave-uniform base + lane*16
static __device__ __forceinline__ void async_ld(const ushort_t* g, ushort_t* l) {
    __builtin_amdgcn_global_load_lds(
        (const __attribute__((address_space(1))) unsigned int*)(const void*)g,
        (__attribute__((address_space(3))) unsigned int*)(void*)l, 16, 0, 0);
}

// ---------------- fp32 weight transpose [O,IK] -> [IK,O] (conv11 only) ----------------
__global__ __launch_bounds__(256) void repack_w_k(const float* __restrict__ w, float* __restrict__ wre,
                                                  int O, int IK) {
    int gid = blockIdx.x * 256 + threadIdx.x;
    if (gid >= O * IK) return;
    int o = gid / IK;
    int r = gid - o * IK;
    wre[r * O + o] = w[gid];
}

// ---------------- conv11 direct (Cin=3) -> NHWC hi/lo strip T1 [4,20,802,64] ----------------
__global__ __launch_bounds__(256) void conv11_strip_k(const float* __restrict__ X0, const float* __restrict__ W11,
                                                      const float* __restrict__ sc, const float* __restrict__ bi,
                                                      ushort_t* __restrict__ Thi, ushort_t* __restrict__ Tlo, int r0) {
    int gid = blockIdx.x * 256 + threadIdx.x;
    if (gid >= 4 * 20 * 802 * 8) return;
    int c8 = gid & 7;
    int t = gid >> 3;
    int w = t % 802; t /= 802;
    int tr = t % 20;
    int b = t / 20;
    int gr = r0 - 1 + tr;
    int gc = w - 1;
    size_t obase = (((size_t)b * 20 + tr) * 802 + w) * 64 + c8 * 8;
    if (gr < 0 || gr >= 288 || gc < 0 || gc >= 800) {
#pragma unroll
        for (int j = 0; j < 8; ++j) { Thi[obase + j] = 0; Tlo[obase + j] = 0; }
        return;
    }
    float acc[8];
#pragma unroll
    for (int j = 0; j < 8; ++j) acc[j] = 0.f;
#pragma unroll
    for (int ci = 0; ci < 3; ++ci) {
        const float* inc = X0 + (size_t)(b * 3 + ci) * 288 * 800;
#pragma unroll
        for (int kh = 0; kh < 3; ++kh) {
            int ih = gr + kh - 1;
            if (ih < 0 || ih >= 288) continue;
#pragma unroll
            for (int kw = 0; kw < 3; ++kw) {
                int iw = gc + kw - 1;
                if (iw < 0 || iw >= 800) continue;
                float v = inc[ih * 800 + iw];
                float wf[8];
                ld8f(W11 + (ci * 9 + kh * 3 + kw) * 64 + c8 * 8, wf);
#pragma unroll
                for (int j = 0; j < 8; ++j) acc[j] = fmaf(v, wf[j], acc[j]);
            }
        }
    }
#pragma unroll
    for (int j = 0; j < 8; ++j) {
        int n = c8 * 8 + j;
        float r = acc[j] * sc[n] + bi[n];
        r = r > 0.f ? r : 0.f;
        split_store(r, Thi, Tlo, obase + j);
    }
}

// ---------------- MFMA weight repack: [O,I,taps] fp32 -> hi/lo bf16 [t][n][k] ----------------
__global__ __launch_bounds__(256) void repack_wmfma_k(const float* __restrict__ w, ushort_t* __restrict__ whi,
                                                      ushort_t* __restrict__ wlo, int N, int Cin, int taps) {
    int gid = blockIdx.x * 256 + threadIdx.x;
    if (gid >= N * Cin * taps) return;
    int o = gid / (Cin * taps);
    int r = gid - o * Cin * taps;
    int i = r / taps;
    int t = r - i * taps;
    float x = w[gid];
    size_t d = ((size_t)t * N + o) * Cin + i;
    ushort_t h = f2bh(x);
    whi[d] = h;
    wlo[d] = f2bh(x - bh2f(h));
}

// ---------------- generic vertical 2x maxpool on NHWC hi/lo ----------------
__global__ __launch_bounds__(256) void vpool2_k(const ushort_t* __restrict__ shi, const ushort_t* __restrict__ slo,
                                                ushort_t* __restrict__ dhi, ushort_t* __restrict__ dlo,
                                                int Hs, int Wp, int C, int Hop, int Wop, int pad, int pr0) {
    int total = 4 * (Hs >> 1) * Wp * C;
    int gid = blockIdx.x * 256 + threadIdx.x;
    if (gid >= total) return;
    int c = gid % C;
    int t = gid / C;
    int w = t % Wp; t /= Wp;
    int hp = t % (Hs >> 1);
    int b = t / (Hs >> 1);
    size_t a0 = (((size_t)b * Hs + 2 * hp) * Wp + w) * C + c;
    size_t a1 = a0 + (size_t)Wp * C;
    float v0 = bh2f(shi[a0]) + bh2f(slo[a0]);
    float v1 = bh2f(shi[a1]) + bh2f(slo[a1]);
    float v = fmaxf(v0, v1);
    size_t d = (((size_t)b * Hop + pr0 + hp + pad) * Wop + (w + pad)) * C + c;
    split_store(v, dhi, dlo, d);
}

// ---------------- generic MFMA conv (split-bf16 hi/lo, 3-MFMA), global_load_lds staging ----------------
// Block tile 128 x (NJ*32). NJ=4: waves compute 64x64. NJ=2: 64x32 (conv12).
// Staging: wave role 0..3 -> {A-hi, A-lo, B-hi, B-lo}; 8 (4 for NJ=2 B) async 1KB issues/chunk.
// LDS layout contiguous (slot = row*4 + c, 16B slots); fetch-side swizzle c=(q+sigma(row))&3,
// sigma(row)=(row>>1)&3 -> fragment ds_read_b128 conflict degree equals R8's padded layout.
// MODE 0: NHWC padded hi/lo out. MODE 1: +horizontal maxpool. MODE 2: NCHW fp32 out.
template <int MODE, int NJ>
__global__ __launch_bounds__(256) void mfma_conv_k(
    const ushort_t* __restrict__ Ahi, const ushort_t* __restrict__ Alo,
    const ushort_t* __restrict__ Whi, const ushort_t* __restrict__ Wlo,
    const float* __restrict__ sc, const float* __restrict__ bi,
    ushort_t* __restrict__ Ohi, ushort_t* __restrict__ Olo, float* __restrict__ Fo,
    int M, int Wimg, int HS, int h0,
    int HpIn, int WpIn, int Cin, int ih0, int iph, int ipw, int dil, int taps,
    int N, int obst, int oh0, int oph, int opw, int WpOut) {
    constexpr int NT = NJ * 32;
    __shared__ ushort_t sA0[128 * 32], sA1[128 * 32];
    __shared__ ushort_t sB0[NT * 32], sB1[NT * 32];

    int tid = threadIdx.x;
    int m0 = blockIdx.x * 128;
    int n0 = blockIdx.y * NT;

    int wid = tid >> 6, lane = tid & 63;
    int moff = (wid >> 1) * 64;
    int noff = (wid & 1) * (NJ * 16);
    int lm = lane & 15, quad = lane >> 4;

    const int lgC = 31 - __clz(Cin);
    // staging lane decomposition + fetch-side swizzle
    int lr16 = lane >> 2;                               // row-in-16 (0..15)
    int lq = ((lane & 3) - ((lr16 >> 1) & 3)) & 3;      // global quarter this lane fetches
    int qoff = lq * 8;                                  // elems

    const ushort_t* gplane;
    ushort_t* lplane;
    if (wid == 0)      { gplane = Ahi; lplane = sA0; }
    else if (wid == 1) { gplane = Alo; lplane = sA1; }
    else if (wid == 2) { gplane = Whi; lplane = sB0; }
    else               { gplane = Wlo; lplane = sB1; }
    bool isA = (wid < 2);

    // A-staging: per-lane pixel index for each of its 8 rows
    int pix[8];
    if (isA) {
#pragma unroll
        for (int j = 0; j < 8; ++j) {
            int R = j * 16 + lr16;
            int am = m0 + R;
            if (am >= M) am = M - 1;
            int aw2 = am % Wimg;
            int tt = am / Wimg;
            int hh = h0 + tt % HS;
            int bb2 = tt / HS;
            pix[j] = (bb2 * HpIn + (hh - ih0 + iph)) * WpIn + (aw2 + ipw);
        }
    }
    int nbase = n0 + lr16;  // B row for j=0

    // fragment-read swizzled column offset (lane-constant)
    int cA8 = ((quad + ((lm >> 1) & 3)) & 3) * 8;

    facc4 acc[4][NJ];
#pragma unroll
    for (int i = 0; i < 4; ++i)
#pragma unroll
        for (int j = 0; j < NJ; ++j) acc[i][j] = (facc4)(0.f);

    for (int t = 0; t < taps; ++t) {
        int dh = 0, dw = 0;
        if (taps == 9) {
            dh = (t / 3 - 1) * dil;
            dw = (t % 3 - 1) * dil;
        }
        int dhw = dh * WpIn + dw;
        long btap = (long)t * N;
        for (int k0 = 0; k0 < Cin; k0 += 32) {
            if (isA) {
#pragma unroll
                for (int j = 0; j < 8; ++j) {
                    long ga = ((long)(pix[j] + dhw) << lgC) + (qoff + k0);
                    async_ld(gplane + ga, lplane + j * 512);
                }
            } else {
#pragma unroll
                for (int j = 0; j < NJ * 2; ++j) {
                    long gb = ((btap + nbase + j * 16) << lgC) + (qoff + k0);
                    async_ld(gplane + gb, lplane + j * 512);
                }
            }
            __syncthreads();  // drains vmcnt(0): all async LDS writes landed
            short8x afh[4], afl[4], bfh[NJ], bfl[NJ];
#pragma unroll
            for (int mi = 0; mi < 4; ++mi) {
                int base = (moff + mi * 16 + lm) * 32 + cA8;
                afh[mi] = *(const short8x*)&sA0[base];
                afl[mi] = *(const short8x*)&sA1[base];
            }
#pragma unroll
            for (int nj = 0; nj < NJ; ++nj) {
                int base = (noff + nj * 16 + lm) * 32 + cA8;
                bfh[nj] = *(const short8x*)&sB0[base];
                bfl[nj] = *(const short8x*)&sB1[base];
            }
#pragma unroll
            for (int mi = 0; mi < 4; ++mi)
#pragma unroll
                for (int nj = 0; nj < NJ; ++nj) {
                    acc[mi][nj] = __builtin_amdgcn_mfma_f32_16x16x32_bf16(afh[mi], bfh[nj], acc[mi][nj], 0, 0, 0);
                    acc[mi][nj] = __builtin_amdgcn_mfma_f32_16x16x32_bf16(afl[mi], bfh[nj], acc[mi][nj], 0, 0, 0);
                    acc[mi][nj] = __builtin_amdgcn_mfma_f32_16x16x32_bf16(afh[mi], bfl[nj], acc[mi][nj], 0, 0, 0);
                }
            __syncthreads();
        }
    }

#pragma unroll
    for (int mi = 0; mi < 4; ++mi)
#pragma unroll
        for (int nj = 0; nj < NJ; ++nj) {
            int nglob = n0 + noff + nj * 16 + lm;
            float s = sc[nglob];
            float bb = bi[nglob];
            if (MODE == 1) {
#pragma unroll
                for (int rg = 0; rg < 4; rg += 2) {
                    int mg = m0 + moff + mi * 16 + quad * 4 + rg;
                    if (mg >= M) continue;
                    float v0 = acc[mi][nj][rg] * s + bb;
                    v0 = v0 > 0.f ? v0 : 0.f;
                    float v1 = acc[mi][nj][rg + 1] * s + bb;
                    v1 = v1 > 0.f ? v1 : 0.f;
                    float v = fmaxf(v0, v1);
                    int wq = mg % Wimg;
                    int tq = mg / Wimg;
                    int hq = h0 + tq % HS;
                    int bq = tq / HS;
                    size_t a = ((size_t)bq * obst + (size_t)(hq - oh0) * WpOut + (wq >> 1)) * N + nglob;
                    split_store(v, Ohi, Olo, a);
                }
            } else {
#pragma unroll
                for (int rg = 0; rg < 4; ++rg) {
                    int mg = m0 + moff + mi * 16 + quad * 4 + rg;
                    if (mg >= M) continue;
                    float v = acc[mi][nj][rg] * s + bb;
                    v = v > 0.f ? v : 0.f;
                    int wq = mg % Wimg;
                    int tq = mg / Wimg;
                    int hq = h0 + tq % HS;
                    int bq = tq / HS;
                    if (MODE == 0) {
                        size_t a = ((size_t)bq * obst + (size_t)(hq - oh0 + oph) * WpOut + (wq + opw)) * N + nglob;
                        split_store(v, Ohi, Olo, a);
                    } else {
                        size_t a = (((size_t)bq * N + nglob) * HS + (hq - h0)) * Wimg + wq;
                        Fo[a] = v;
                    }
                }
            }
        }
}

// ========================= scans + tail (proven) =========================
__global__ __launch_bounds__(256) void repack_scan_k(const float* __restrict__ w, float* __restrict__ wre) {
    int gid = blockIdx.x * 256 + threadIdx.x;
    if (gid >= 128 * 128 * 9) return;
    int o = gid / 1152;
    int r = gid - o * 1152;
    wre[r * 128 + o] = w[gid];
}

__global__ __launch_bounds__(256) void scan_row_k(float* __restrict__ F, const float* __restrict__ wsc, int hp, int hc) {
    __shared__ float sm[128 * 12];
    int b = blockIdx.x / 25;
    int w0 = (blockIdx.x % 25) * 4;
    int tid = threadIdx.x;
    const float* Fp = F + ((size_t)(b * 128) * 36 + hp) * 100;
    for (int i = tid; i < 1536; i += 256) {
        int ci = i / 12;
        int j = i - ci * 12;
        int iw = w0 - 4 + j;
        sm[i] = (iw >= 0 && iw < 100) ? Fp[(size_t)ci * 3600 + iw] : 0.f;
    }
    __syncthreads();
    int o = tid & 127;
    int half = tid >> 7;
    float a0 = 0.f, a1 = 0.f;
    for (int ci = 0; ci < 128; ++ci) {
        const float* s = sm + ci * 12 + half * 2;
        const float* wp = wsc + ci * 9 * 128 + o;
#pragma unroll
        for (int k = 0; k < 9; ++k) {
            float wt = wp[k * 128];
            a0 = fmaf(s[k], wt, a0);
            a1 = fmaf(s[k + 1], wt, a1);
        }
    }
    int w = w0 + half * 2;
    float* outp = F + ((size_t)(b * 128 + o) * 36 + hc) * 100 + w;
    outp[0] += a0 > 0.f ? a0 : 0.f;
    outp[1] += a1 > 0.f ? a1 : 0.f;
}

// column scan on transposed FT [4,128,100,36] (h contiguous): coalesced staging
__global__ __launch_bounds__(256) void scan_colT_k(float* __restrict__ FT, const float* __restrict__ wsc, int wp_, int wc) {
    __shared__ float sm[128 * 12];
    int b = blockIdx.x / 9;
    int h0 = (blockIdx.x % 9) * 4;
    int tid = threadIdx.x;
    const float* Fp = FT + (size_t)(b * 128) * 3600 + (size_t)wp_ * 36;
    for (int i = tid; i < 1536; i += 256) {
        int ci = i / 12;
        int j = i - ci * 12;
        int ih = h0 - 4 + j;
        sm[i] = (ih >= 0 && ih < 36) ? Fp[(size_t)ci * 3600 + ih] : 0.f;
    }
    __syncthreads();
    int o = tid & 127;
    int half = tid >> 7;
    float a0 = 0.f, a1 = 0.f;
    for (int ci = 0; ci < 128; ++ci) {
        const float* s = sm + ci * 12 + half * 2;
        const float* wp = wsc + ci * 9 * 128 + o;
#pragma unroll
        for (int k = 0; k < 9; ++k) {
            float wt = wp[k * 128];
            a0 = fmaf(s[k], wt, a0);
            a1 = fmaf(s[k + 1], wt, a1);
        }
    }
    int h = h0 + half * 2;
    float* outp = FT + ((size_t)(b * 128 + o) * 100 + wc) * 36 + h;
    outp[0] += a0 > 0.f ? a0 : 0.f;
    outp[1] += a1 > 0.f ? a1 : 0.f;
}

// F [4,128,36,100] -> FT [4,128,100,36] (coalesced writes)
__global__ __launch_bounds__(256) void transpose_fwd_k(const float* __restrict__ F, float* __restrict__ FT) {
    int gid = blockIdx.x * 256 + threadIdx.x;
    if (gid >= 4 * 128 * 3600) return;
    int h = gid % 36;
    int t = gid / 36;
    int w = t % 100;
    int bc = t / 100;
    FT[gid] = F[(size_t)bc * 3600 + h * 100 + w];
}
// FT -> F (coalesced writes)
__global__ __launch_bounds__(256) void transpose_bwd_k(const float* __restrict__ FT, float* __restrict__ F) {
    int gid = blockIdx.x * 256 + threadIdx.x;
    if (gid >= 4 * 128 * 3600) return;
    int w = gid % 100;
    int t = gid / 100;
    int h = t % 36;
    int bc = t / 36;
    F[gid] = FT[(size_t)bc * 3600 + w * 36 + h];
}

__global__ __launch_bounds__(256) void conv8_k(const float* __restrict__ F, const float* __restrict__ w8,
                                               const float* __restrict__ b8, float* __restrict__ G) {
    int gid = blockIdx.x * 256 + threadIdx.x;
    if (gid >= NB * 3600) return;
    int hw = gid % 3600;
    int b = gid / 3600;
    float acc[5];
#pragma unroll
    for (int c = 0; c < 5; ++c) acc[c] = b8[c];
    const float* Fb = F + (size_t)b * 128 * 3600 + hw;
    for (int ci = 0; ci < 128; ++ci) {
        float v = Fb[(size_t)ci * 3600];
#pragma unroll
        for (int c = 0; c < 5; ++c) acc[c] = fmaf(v, w8[c * 128 + ci], acc[c]);
    }
#pragma unroll
    for (int c = 0; c < 5; ++c) G[(size_t)(b * 5 + c) * 3600 + hw] = acc[c];
}

__global__ __launch_bounds__(256) void resize_softmax_k(const float* __restrict__ G, float* __restrict__ out) {
    int gid = blockIdx.x * 256 + threadIdx.x;
    if (gid >= NB * 288 * 800) return;
    int ox = gid % 800;
    int t = gid / 800;
    int oy = t % 288;
    int b = t / 288;
    float fy = oy * (35.0f / 287.0f);
    int y0 = (int)fy; if (y0 > 34) y0 = 34;
    int y1 = y0 + 1;
    float wy = fy - y0;
    float fx = ox * (99.0f / 799.0f);
    int x0 = (int)fx; if (x0 > 98) x0 = 98;
    int x1 = x0 + 1;
    float wx = fx - x0;
    const float* Gb = G + (size_t)b * 5 * 3600;
    float v[5];
    float m = -1e30f;
#pragma unroll
    for (int c = 0; c < 5; ++c) {
        const float* Gc = Gb + (size_t)c * 3600;
        float a = Gc[y0 * 100 + x0] * (1.f - wx) + Gc[y0 * 100 + x1] * wx;
        float bb = Gc[y1 * 100 + x0] * (1.f - wx) + Gc[y1 * 100 + x1] * wx;
        v[c] = a * (1.f - wy) + bb * wy;
        m = fmaxf(m, v[c]);
    }
    float sum = 0.f;
#pragma unroll
    for (int c = 0; c < 5; ++c) { v[c] = expf(v[c] - m); sum += v[c]; }
    float inv = 1.f / sum;
#pragma unroll
    for (int c = 0; c < 5; ++c) out[((size_t)(b * 5 + c) * 288 + oy) * 800 + ox] = v[c] * inv;
}

__global__ __launch_bounds__(256) void pool_softmax_k(const float* __restrict__ G, float* __restrict__ P) {
    int gid = blockIdx.x * 256 + threadIdx.x;
    if (gid >= NB * 18 * 50) return;
    int pw = gid % 50;
    int t = gid / 50;
    int ph = t % 18;
    int b = t / 18;
    float s5[5] = {0.f, 0.f, 0.f, 0.f, 0.f};
    const float* Gb = G + (size_t)b * 5 * 3600;
#pragma unroll
    for (int dy = 0; dy < 2; ++dy) {
#pragma unroll
        for (int dx = 0; dx < 2; ++dx) {
            int hw = (2 * ph + dy) * 100 + (2 * pw + dx);
            float v[5], m = -1e30f, sum = 0.f;
#pragma unroll
            for (int c = 0; c < 5; ++c) { v[c] = Gb[(size_t)c * 3600 + hw]; m = fmaxf(m, v[c]); }
#pragma unroll
            for (int c = 0; c < 5; ++c) { v[c] = expf(v[c] - m); sum += v[c]; }
            float inv = 1.f / sum;
#pragma unroll
            for (int c = 0; c < 5; ++c) s5[c] += v[c] * inv;
        }
    }
#pragma unroll
    for (int c = 0; c < 5; ++c) P[b * 4500 + c * 900 + ph * 50 + pw] = s5[c] * 0.25f;
}

__global__ __launch_bounds__(256) void fc1_k(const float* __restrict__ P, const float* __restrict__ fw9,
                                             const float* __restrict__ fb9, float* __restrict__ H1) {
    int wid = blockIdx.x * 4 + (threadIdx.x >> 6);
    int lane = threadIdx.x & 63;
    if (wid >= 512) return;
    int b = wid >> 7;
    int o = wid & 127;
    const float* wr = fw9 + (size_t)o * 4500;
    const float* pr = P + b * 4500;
    float acc = 0.f;
    for (int i = lane; i < 4500; i += 64) acc = fmaf(wr[i], pr[i], acc);
    for (int s = 32; s > 0; s >>= 1) acc += __shfl_down(acc, s, 64);
    if (lane == 0) {
        float r = acc + fb9[o];
        H1[b * 128 + o] = r > 0.f ? r : 0.f;
    }
}

__global__ __launch_bounds__(64) void fc2_k(const float* __restrict__ H1, const float* __restrict__ fw10,
                                            const float* __restrict__ fb10, float* __restrict__ dout) {
    int t = threadIdx.x;
    if (t >= 16) return;
    int b = t >> 2;
    int o = t & 3;
    float acc = fb10[o];
    for (int i = 0; i < 128; ++i) acc = fmaf(H1[b * 128 + i], fw10[o * 128 + i], acc);
    dout[4608000 + t] = 1.f / (1.f + expf(-acc));
}

// ======================================================================================
static inline int ceildiv(int a, int b) { return (a + b - 1) / b; }

extern "C" void kernel_launch(void* const* d_in, const int* in_sizes, int n_in,
                              void* d_out, int out_size, void* d_ws, size_t ws_size,
                              hipStream_t stream) {
    (void)in_sizes; (void)n_in; (void)out_size; (void)ws_size;
    char* U = (char*)d_ws;                 // 19,000,064 B utility region
    char* V = U + 19000064;                // 103,424,000 B activation arena

    // ---- U lifetimes ----
    float* W11f = (float*)(U);                       // 6912 B
    ushort_t* WM12 = (ushort_t*)(U + 8192);          // 9*64*64/plane
    ushort_t* WM21 = (ushort_t*)(U + 155648);        // 9*128*64/plane
    ushort_t* WM22 = (ushort_t*)(U + 450560);        // 9*128*128/plane
    ushort_t* T1hi = (ushort_t*)(U + 1050624);       // [4,20,802,64] 8,212,480 B/plane
    ushort_t* T1lo = (ushort_t*)(U + 1050624 + 8212480);
    ushort_t* T3hi = (ushort_t*)(U + 1050624);       // [4,20,402,128] 8,232,960 B/plane
    ushort_t* T3lo = (ushort_t*)(U + 1050624 + 8232960);
    ushort_t* WMa = (ushort_t*)(U);
    ushort_t* WMb = (ushort_t*)(U + 4718592);
    float* WSC = (float*)(U);
    float* G = (float*)(U + 2359296);
    float* P = (float*)(U + 2647296);
    float* H1 = (float*)(U + 2719296);

    // ---- V lifetimes ----
    ushort_t* Xhi = (ushort_t*)(V);                  // [4,74,202,128] pad(1)
    ushort_t* Xlo = (ushort_t*)(V + 15306752);
    ushort_t* S1hi = (ushort_t*)(V + 30613504);      // [4,146,402,64] pad(1) 30,050,304 B/plane
    ushort_t* S1lo = (ushort_t*)(V + 60663808);
    ushort_t* T2hi = (ushort_t*)(V + 90714112);      // 3,686,400 B/plane
    ushort_t* T2lo = (ushort_t*)(V + 90714112 + 3686400);
    ushort_t* Yhi = (ushort_t*)(V + 30613504);       // conv31 out [4,74,202,256]
    ushort_t* Ylo = (ushort_t*)(V + 61227008);
    ushort_t* Zhi = (ushort_t*)(V + 91840512);       // conv32 strip
    ushort_t* Zlo = (ushort_t*)(V + 97632256);
    ushort_t* HPhi = (ushort_t*)(V);                 // conv33+hpool out [4,72,100,256]
    ushort_t* HPlo = (ushort_t*)(V + 14745600);
    ushort_t* PAhi = (ushort_t*)(V + 30613504);      // pooled stage3 [4,44,108,256] pad(4)
    ushort_t* PAlo = (ushort_t*)(V + 40345600);
    ushort_t* SBhi = (ushort_t*)(V + 50077696);      // 512ch slotB [4,44,108,512]
    ushort_t* SBlo = (ushort_t*)(V + 69541888);
    ushort_t* SAhi = (ushort_t*)(V);                 // 512ch slotA
    ushort_t* SAlo = (ushort_t*)(V + 19464192);
    ushort_t* C6hi = (ushort_t*)(V + 38928384);      // conv6 out [4,36,100,1024]
    ushort_t* C6lo = (ushort_t*)(V + 68419584);
    float* F = (float*)(V);                          // SCNN state fp32 NCHW [0, 7,372,800)
    float* FT = (float*)(V + 7372800);               // transposed state [7.37M, 14.75M)

    const float* X0 = (const float*)d_in[0];
    auto din = [&](int i) { return (const float*)d_in[i]; };
    auto wm_lo = [&](ushort_t* base, int taps, int N, int C) { return base + (size_t)taps * N * C; };

    // ================= stage1 =================
    repack_w_k<<<ceildiv(27 * 64, 256), 256, 0, stream>>>(din(1), W11f, 64, 27);
    repack_wmfma_k<<<ceildiv(64 * 64 * 9, 256), 256, 0, stream>>>(din(4), WM12, wm_lo(WM12, 9, 64, 64), 64, 64, 9);
    hipMemsetAsync(V + 30613504, 0, 60100608, stream);  // S1 padding
    for (int s = 0; s < 16; ++s) {
        int r0 = s * 18;
        conv11_strip_k<<<2005, 256, 0, stream>>>(X0, W11f, din(2), din(3), T1hi, T1lo, r0);
        mfma_conv_k<1, 2><<<dim3(450, 1), 256, 0, stream>>>(
            T1hi, T1lo, WM12, wm_lo(WM12, 9, 64, 64), din(5), din(6), T2hi, T2lo, nullptr,
            57600, 800, 18, r0, 20, 802, 64, r0, 1, 1, 1, 9, 64, 18 * 400, r0, 0, 0, 400);
        vpool2_k<<<ceildiv(4 * 9 * 400 * 64, 256), 256, 0, stream>>>(
            T2hi, T2lo, S1hi, S1lo, 18, 400, 64, 146, 402, 1, r0 / 2);
    }
    // ================= stage2 =================
    repack_wmfma_k<<<ceildiv(128 * 64 * 9, 256), 256, 0, stream>>>(din(7), WM21, wm_lo(WM21, 9, 128, 64), 128, 64, 9);
    repack_wmfma_k<<<ceildiv(128 * 128 * 9, 256), 256, 0, stream>>>(din(10), WM22, wm_lo(WM22, 9, 128, 128), 128, 128, 9);
    hipMemsetAsync(V, 0, 30613504, stream);  // X padding
    for (int s = 0; s < 8; ++s) {
        int r0 = s * 18;
        int hstart = r0 - 1 < 0 ? 0 : r0 - 1;
        int hend = r0 + 19 > 144 ? 144 : r0 + 19;
        int rows = hend - hstart;
        int M21 = 4 * rows * 400;
        hipMemsetAsync(U + 1050624, 0, 16465920, stream);  // T3 both planes
        mfma_conv_k<0, 4><<<dim3(ceildiv(M21, 128), 1), 256, 0, stream>>>(
            S1hi, S1lo, WM21, wm_lo(WM21, 9, 128, 64), din(8), din(9), T3hi, T3lo, nullptr,
            M21, 400, rows, hstart, 146, 402, 64, 0, 1, 1, 1, 9, 128, 20 * 402, r0 - 1, 0, 1, 402);
        mfma_conv_k<1, 4><<<dim3(225, 1), 256, 0, stream>>>(
            T3hi, T3lo, WM22, wm_lo(WM22, 9, 128, 128), din(11), din(12), T2hi, T2lo, nullptr,
            28800, 400, 18, r0, 20, 402, 128, r0 - 1, 0, 1, 1, 9, 128, 18 * 200, r0, 0, 0, 200);
        vpool2_k<<<ceildiv(4 * 9 * 200 * 128, 256), 256, 0, stream>>>(
            T2hi, T2lo, Xhi, Xlo, 18, 200, 128, 74, 202, 1, r0 / 2);
    }

    // ================= conv31 =================
    repack_wmfma_k<<<ceildiv(256 * 128 * 9, 256), 256, 0, stream>>>(din(13), WMa, wm_lo(WMa, 9, 256, 128), 256, 128, 9);
    hipMemsetAsync(V + 30613504, 0, 61227008, stream);
    mfma_conv_k<0, 4><<<dim3(450, 2), 256, 0, stream>>>(
        Xhi, Xlo, WMa, wm_lo(WMa, 9, 256, 128), din(14), din(15), Yhi, Ylo, nullptr,
        57600, 200, 72, 0, 74, 202, 128, 0, 1, 1, 1, 9, 256, 74 * 202, 0, 1, 1, 202);
    // ================= conv32/conv33+hpool strips =================
    repack_wmfma_k<<<ceildiv(256 * 256 * 9, 256), 256, 0, stream>>>(din(16), WMa, wm_lo(WMa, 9, 256, 256), 256, 256, 9);
    repack_wmfma_k<<<ceildiv(256 * 256 * 9, 256), 256, 0, stream>>>(din(19), WMb, wm_lo(WMb, 9, 256, 256), 256, 256, 9);
    for (int s = 0; s < 6; ++s) {
        int h0s = s * 12;
        int hstart = h0s - 1 < 0 ? 0 : h0s - 1;
        int hend = h0s + 13 > 72 ? 72 : h0s + 13;
        int rows = hend - hstart;
        int M32 = 4 * rows * 200;
        hipMemsetAsync(V + 91840512, 0, 11583488, stream);
        mfma_conv_k<0, 4><<<dim3(ceildiv(M32, 128), 2), 256, 0, stream>>>(
            Yhi, Ylo, WMa, wm_lo(WMa, 9, 256, 256), din(17), din(18), Zhi, Zlo, nullptr,
            M32, 200, rows, hstart, 74, 202, 256, 0, 1, 1, 1, 9, 256, 14 * 202, h0s - 1, 0, 1, 202);
        mfma_conv_k<1, 4><<<dim3(75, 2), 256, 0, stream>>>(
            Zhi, Zlo, WMb, wm_lo(WMb, 9, 256, 256), din(20), din(21), HPhi, HPlo, nullptr,
            9600, 200, 12, h0s, 14, 202, 256, h0s - 1, 0, 1, 1, 9, 256, 72 * 100, 0, 0, 0, 100);
    }
    hipMemsetAsync(V + 30613504, 0, 19464192, stream);
    vpool2_k<<<ceildiv(4 * 36 * 100 * 256, 256), 256, 0, stream>>>(
        HPhi, HPlo, PAhi, PAlo, 72, 100, 256, 44, 108, 4, 0);

    // ================= conv41..conv53 =================
    struct L { int wi, si, bi, dil; };
    static const L l45[5] = {{25, 26, 27, 1}, {28, 29, 30, 1}, {31, 32, 33, 2}, {34, 35, 36, 2}, {37, 38, 39, 2}};
    repack_wmfma_k<<<ceildiv(512 * 256 * 9, 256), 256, 0, stream>>>(din(22), WMa, wm_lo(WMa, 9, 512, 256), 512, 256, 9);
    hipMemsetAsync(V + 50077696, 0, 38928384, stream);
    mfma_conv_k<0, 4><<<dim3(113, 4), 256, 0, stream>>>(
        PAhi, PAlo, WMa, wm_lo(WMa, 9, 512, 256), din(23), din(24), SBhi, SBlo, nullptr,
        14400, 100, 36, 0, 44, 108, 256, 0, 4, 4, 1, 9, 512, 44 * 108, 0, 4, 4, 108);
    hipMemsetAsync(V, 0, 38928384, stream);  // slotA borders
    for (int i = 0; i < 5; ++i) {
        const L& L0 = l45[i];
        repack_wmfma_k<<<ceildiv(512 * 512 * 9, 256), 256, 0, stream>>>(din(L0.wi), WMa, wm_lo(WMa, 9, 512, 512), 512, 512, 9);
        const ushort_t* ih = (i & 1) ? SAhi : SBhi;
        const ushort_t* il = (i & 1) ? SAlo : SBlo;
        ushort_t* oh = (i & 1) ? SBhi : SAhi;
        ushort_t* ol = (i & 1) ? SBlo : SAlo;
        mfma_conv_k<0, 4><<<dim3(113, 4), 256, 0, stream>>>(
            ih, il, WMa, wm_lo(WMa, 9, 512, 512), din(L0.si), din(L0.bi), oh, ol, nullptr,
            14400, 100, 36, 0, 44, 108, 512, 0, 4, 4, L0.dil, 9, 512, 44 * 108, 0, 4, 4, 108);
    }
    repack_wmfma_k<<<ceildiv(1024 * 512 * 9, 256), 256, 0, stream>>>(din(40), WMa, wm_lo(WMa, 9, 1024, 512), 1024, 512, 9);
    mfma_conv_k<0, 4><<<dim3(113, 8), 256, 0, stream>>>(
        SAhi, SAlo, WMa, wm_lo(WMa, 9, 1024, 512), din(41), din(42), C6hi, C6lo, nullptr,
        14400, 100, 36, 0, 44, 108, 512, 0, 4, 4, 4, 9, 1024, 3600, 0, 0, 0, 100);
    repack_wmfma_k<<<ceildiv(128 * 1024, 256), 256, 0, stream>>>(din(43), WMa, wm_lo(WMa, 1, 128, 1024), 128, 1024, 1);
    mfma_conv_k<2, 4><<<dim3(113, 1), 256, 0, stream>>>(
        C6hi, C6lo, WMa, wm_lo(WMa, 1, 128, 1024), din(44), din(45), nullptr, nullptr, F,
        14400, 100, 36, 0, 36, 100, 1024, 0, 0, 0, 1, 1, 128, 0, 0, 0, 0, 0);

    // ================= SCNN scans + tail =================
    for (int j = 0; j < 4; ++j)
        repack_scan_k<<<576, 256, 0, stream>>>(din(46 + j), WSC + (size_t)j * 147456);
    for (int h = 1; h <= 35; ++h)
        scan_row_k<<<100, 256, 0, stream>>>(F, WSC + 0 * 147456, h - 1, h);
    for (int h = 34; h >= 1; --h)
        scan_row_k<<<100, 256, 0, stream>>>(F, WSC + 1 * 147456, h + 1, h);
    transpose_fwd_k<<<7200, 256, 0, stream>>>(F, FT);
    for (int w = 1; w <= 99; ++w)
        scan_colT_k<<<36, 256, 0, stream>>>(FT, WSC + 2 * (size_t)147456, w - 1, w);
    for (int w = 98; w >= 1; --w)
        scan_colT_k<<<36, 256, 0, stream>>>(FT, WSC + 3 * (size_t)147456, w + 1, w);
    transpose_bwd_k<<<7200, 256, 0, stream>>>(FT, F);

    conv8_k<<<ceildiv(NB * 3600, 256), 256, 0, stream>>>(F, din(50), din(51), G);
    resize_softmax_k<<<ceildiv(NB * 288 * 800, 256), 256, 0, stream>>>(G, (float*)d_out);
    pool_softmax_k<<<ceildiv(NB * 18 * 50, 256), 256, 0, stream>>>(G, P);
    fc1_k<<<128, 256, 0, stream>>>(P, din(52), din(53), H1);
    fc2_k<<<1, 64, 0, stream>>>(H1, din(54), din(55), (float*)d_out);
}

// Round 11
// 10408.360 us; speedup vs baseline: 1.7373x; 1.0084x over previous
//
#include <hip/hip_runtime.h>
#include <math.h>

// SCNN lane-detection net on MI355X. Round 11: fix grid starvation in stage2/3 conv.
// R10 analysis: conv21 ran at 63 blocks (63/256 CUs), conv22/32/33 at 150-225 — the
// NJ=4 128x128 tile shrank grid.y to N/128. These ~114 G-MAC layers ran ~25% occupancy.
// Now they use the NJ=2 128x64 tile (grid.y = N/64): 2-4x more blocks. All other
// layers and kernels byte-identical to the passing R10 (10.50 ms).

#define NB 4

typedef unsigned short ushort_t;
typedef __attribute__((ext_vector_type(8))) short short8x;   // 8 bf16 (4 VGPRs)
typedef __attribute__((ext_vector_type(4))) float facc4;     // 4 fp32 acc

static __device__ __forceinline__ ushort_t f2bh(float x) {
    unsigned u = __float_as_uint(x);
    unsigned r = u + 0x7fffu + ((u >> 16) & 1u);
    return (ushort_t)(r >> 16);
}
static __device__ __forceinline__ float bh2f(ushort_t h) {
    return __uint_as_float(((unsigned)h) << 16);
}
static __device__ __forceinline__ void split_store(float v, ushort_t* __restrict__ hi,
                                                   ushort_t* __restrict__ lo, size_t idx) {
    ushort_t h = f2bh(v);
    float l = v - bh2f(h);
    hi[idx] = h;
    lo[idx] = f2bh(l);
}
static __device__ __forceinline__ void ld8f(const float* p, float f[8]) {
    float4 a = *(const float4*)p;
    float4 b = *(const float4*)(p + 4);
    f[0] = a.x; f[1] = a.y; f[2] = a.z; f[3] = a.w;
    f[4] = b.x; f[5] = b.y; f[6] = b.z; f[7] = b.w;
}
// async global->LDS, 16 B per lane; LDS dst = wave-uniform base + lane*16
static __device__ __forceinline__ void async_ld(const ushort_t* g, ushort_t* l) {
    __builtin_amdgcn_global_load_lds(
        (const __attribute__((address_space(1))) unsigned int*)(const void*)g,
        (__attribute__((address_space(3))) unsigned int*)(void*)l, 16, 0, 0);
}

// ---------------- fp32 weight transpose [O,IK] -> [IK,O] (conv11 only) ----------------
__global__ __launch_bounds__(256) void repack_w_k(const float* __restrict__ w, float* __restrict__ wre,
                                                  int O, int IK) {
    int gid = blockIdx.x * 256 + threadIdx.x;
    if (gid >= O * IK) return;
    int o = gid / IK;
    int r = gid - o * IK;
    wre[r * O + o] = w[gid];
}

// ---------------- conv11 direct (Cin=3) -> NHWC hi/lo strip T1 [4,20,802,64] ----------------
__global__ __launch_bounds__(256) void conv11_strip_k(const float* __restrict__ X0, const float* __restrict__ W11,
                                                      const float* __restrict__ sc, const float* __restrict__ bi,
                                                      ushort_t* __restrict__ Thi, ushort_t* __restrict__ Tlo, int r0) {
    int gid = blockIdx.x * 256 + threadIdx.x;
    if (gid >= 4 * 20 * 802 * 8) return;
    int c8 = gid & 7;
    int t = gid >> 3;
    int w = t % 802; t /= 802;
    int tr = t % 20;
    int b = t / 20;
    int gr = r0 - 1 + tr;
    int gc = w - 1;
    size_t obase = (((size_t)b * 20 + tr) * 802 + w) * 64 + c8 * 8;
    if (gr < 0 || gr >= 288 || gc < 0 || gc >= 800) {
#pragma unroll
        for (int j = 0; j < 8; ++j) { Thi[obase + j] = 0; Tlo[obase + j] = 0; }
        return;
    }
    float acc[8];
#pragma unroll
    for (int j = 0; j < 8; ++j) acc[j] = 0.f;
#pragma unroll
    for (int ci = 0; ci < 3; ++ci) {
        const float* inc = X0 + (size_t)(b * 3 + ci) * 288 * 800;
#pragma unroll
        for (int kh = 0; kh < 3; ++kh) {
            int ih = gr + kh - 1;
            if (ih < 0 || ih >= 288) continue;
#pragma unroll
            for (int kw = 0; kw < 3; ++kw) {
                int iw = gc + kw - 1;
                if (iw < 0 || iw >= 800) continue;
                float v = inc[ih * 800 + iw];
                float wf[8];
                ld8f(W11 + (ci * 9 + kh * 3 + kw) * 64 + c8 * 8, wf);
#pragma unroll
                for (int j = 0; j < 8; ++j) acc[j] = fmaf(v, wf[j], acc[j]);
            }
        }
    }
#pragma unroll
    for (int j = 0; j < 8; ++j) {
        int n = c8 * 8 + j;
        float r = acc[j] * sc[n] + bi[n];
        r = r > 0.f ? r : 0.f;
        split_store(r, Thi, Tlo, obase + j);
    }
}

// ---------------- MFMA weight repack: [O,I,taps] fp32 -> hi/lo bf16 [t][n][k] ----------------
__global__ __launch_bounds__(256) void repack_wmfma_k(const float* __restrict__ w, ushort_t* __restrict__ whi,
                                                      ushort_t* __restrict__ wlo, int N, int Cin, int taps) {
    int gid = blockIdx.x * 256 + threadIdx.x;
    if (gid >= N * Cin * taps) return;
    int o = gid / (Cin * taps);
    int r = gid - o * Cin * taps;
    int i = r / taps;
    int t = r - i * taps;
    float x = w[gid];
    size_t d = ((size_t)t * N + o) * Cin + i;
    ushort_t h = f2bh(x);
    whi[d] = h;
    wlo[d] = f2bh(x - bh2f(h));
}

// ---------------- generic vertical 2x maxpool on NHWC hi/lo ----------------
__global__ __launch_bounds__(256) void vpool2_k(const ushort_t* __restrict__ shi, const ushort_t* __restrict__ slo,
                                                ushort_t* __restrict__ dhi, ushort_t* __restrict__ dlo,
                                                int Hs, int Wp, int C, int Hop, int Wop, int pad, int pr0) {
    int total = 4 * (Hs >> 1) * Wp * C;
    int gid = blockIdx.x * 256 + threadIdx.x;
    if (gid >= total) return;
    int c = gid % C;
    int t = gid / C;
    int w = t % Wp; t /= Wp;
    int hp = t % (Hs >> 1);
    int b = t / (Hs >> 1);
    size_t a0 = (((size_t)b * Hs + 2 * hp) * Wp + w) * C + c;
    size_t a1 = a0 + (size_t)Wp * C;
    float v0 = bh2f(shi[a0]) + bh2f(slo[a0]);
    float v1 = bh2f(shi[a1]) + bh2f(slo[a1]);
    float v = fmaxf(v0, v1);
    size_t d = (((size_t)b * Hop + pr0 + hp + pad) * Wop + (w + pad)) * C + c;
    split_store(v, dhi, dlo, d);
}

// ---------------- generic MFMA conv (split-bf16 hi/lo, 3-MFMA), global_load_lds staging ----------------
// Block tile 128 x (NJ*32). NJ=4: waves compute 64x64. NJ=2: 64x32.
// Staging: wave role 0..3 -> {A-hi, A-lo, B-hi, B-lo}; async width-16 issues.
// Contiguous LDS with fetch-side swizzle (conflict-equal to padded layout).
// MODE 0: NHWC padded hi/lo out. MODE 1: +horizontal maxpool. MODE 2: NCHW fp32 out.
template <int MODE, int NJ>
__global__ __launch_bounds__(256) void mfma_conv_k(
    const ushort_t* __restrict__ Ahi, const ushort_t* __restrict__ Alo,
    const ushort_t* __restrict__ Whi, const ushort_t* __restrict__ Wlo,
    const float* __restrict__ sc, const float* __restrict__ bi,
    ushort_t* __restrict__ Ohi, ushort_t* __restrict__ Olo, float* __restrict__ Fo,
    int M, int Wimg, int HS, int h0,
    int HpIn, int WpIn, int Cin, int ih0, int iph, int ipw, int dil, int taps,
    int N, int obst, int oh0, int oph, int opw, int WpOut) {
    constexpr int NT = NJ * 32;
    __shared__ ushort_t sA0[128 * 32], sA1[128 * 32];
    __shared__ ushort_t sB0[NT * 32], sB1[NT * 32];

    int tid = threadIdx.x;
    int m0 = blockIdx.x * 128;
    int n0 = blockIdx.y * NT;

    int wid = tid >> 6, lane = tid & 63;
    int moff = (wid >> 1) * 64;
    int noff = (wid & 1) * (NJ * 16);
    int lm = lane & 15, quad = lane >> 4;

    const int lgC = 31 - __clz(Cin);
    int lr16 = lane >> 2;                               // row-in-16 (0..15)
    int lq = ((lane & 3) - ((lr16 >> 1) & 3)) & 3;      // fetch-side swizzle
    int qoff = lq * 8;

    const ushort_t* gplane;
    ushort_t* lplane;
    if (wid == 0)      { gplane = Ahi; lplane = sA0; }
    else if (wid == 1) { gplane = Alo; lplane = sA1; }
    else if (wid == 2) { gplane = Whi; lplane = sB0; }
    else               { gplane = Wlo; lplane = sB1; }
    bool isA = (wid < 2);

    int pix[8];
    if (isA) {
#pragma unroll
        for (int j = 0; j < 8; ++j) {
            int R = j * 16 + lr16;
            int am = m0 + R;
            if (am >= M) am = M - 1;
            int aw2 = am % Wimg;
            int tt = am / Wimg;
            int hh = h0 + tt % HS;
            int bb2 = tt / HS;
            pix[j] = (bb2 * HpIn + (hh - ih0 + iph)) * WpIn + (aw2 + ipw);
        }
    }
    int nbase = n0 + lr16;

    int cA8 = ((quad + ((lm >> 1) & 3)) & 3) * 8;

    facc4 acc[4][NJ];
#pragma unroll
    for (int i = 0; i < 4; ++i)
#pragma unroll
        for (int j = 0; j < NJ; ++j) acc[i][j] = (facc4)(0.f);

    for (int t = 0; t < taps; ++t) {
        int dh = 0, dw = 0;
        if (taps == 9) {
            dh = (t / 3 - 1) * dil;
            dw = (t % 3 - 1) * dil;
        }
        int dhw = dh * WpIn + dw;
        long btap = (long)t * N;
        for (int k0 = 0; k0 < Cin; k0 += 32) {
            if (isA) {
#pragma unroll
                for (int j = 0; j < 8; ++j) {
                    long ga = ((long)(pix[j] + dhw) << lgC) + (qoff + k0);
                    async_ld(gplane + ga, lplane + j * 512);
                }
            } else {
#pragma unroll
                for (int j = 0; j < NJ * 2; ++j) {
                    long gb = ((btap + nbase + j * 16) << lgC) + (qoff + k0);
                    async_ld(gplane + gb, lplane + j * 512);
                }
            }
            __syncthreads();
            short8x afh[4], afl[4], bfh[NJ], bfl[NJ];
#pragma unroll
            for (int mi = 0; mi < 4; ++mi) {
                int base = (moff + mi * 16 + lm) * 32 + cA8;
                afh[mi] = *(const short8x*)&sA0[base];
                afl[mi] = *(const short8x*)&sA1[base];
            }
#pragma unroll
            for (int nj = 0; nj < NJ; ++nj) {
                int base = (noff + nj * 16 + lm) * 32 + cA8;
                bfh[nj] = *(const short8x*)&sB0[base];
                bfl[nj] = *(const short8x*)&sB1[base];
            }
#pragma unroll
            for (int mi = 0; mi < 4; ++mi)
#pragma unroll
                for (int nj = 0; nj < NJ; ++nj) {
                    acc[mi][nj] = __builtin_amdgcn_mfma_f32_16x16x32_bf16(afh[mi], bfh[nj], acc[mi][nj], 0, 0, 0);
                    acc[mi][nj] = __builtin_amdgcn_mfma_f32_16x16x32_bf16(afl[mi], bfh[nj], acc[mi][nj], 0, 0, 0);
                    acc[mi][nj] = __builtin_amdgcn_mfma_f32_16x16x32_bf16(afh[mi], bfl[nj], acc[mi][nj], 0, 0, 0);
                }
            __syncthreads();
        }
    }

#pragma unroll
    for (int mi = 0; mi < 4; ++mi)
#pragma unroll
        for (int nj = 0; nj < NJ; ++nj) {
            int nglob = n0 + noff + nj * 16 + lm;
            float s = sc[nglob];
            float bb = bi[nglob];
            if (MODE == 1) {
#pragma unroll
                for (int rg = 0; rg < 4; rg += 2) {
                    int mg = m0 + moff + mi * 16 + quad * 4 + rg;
                    if (mg >= M) continue;
                    float v0 = acc[mi][nj][rg] * s + bb;
                    v0 = v0 > 0.f ? v0 : 0.f;
                    float v1 = acc[mi][nj][rg + 1] * s + bb;
                    v1 = v1 > 0.f ? v1 : 0.f;
                    float v = fmaxf(v0, v1);
                    int wq = mg % Wimg;
                    int tq = mg / Wimg;
                    int hq = h0 + tq % HS;
                    int bq = tq / HS;
                    size_t a = ((size_t)bq * obst + (size_t)(hq - oh0) * WpOut + (wq >> 1)) * N + nglob;
                    split_store(v, Ohi, Olo, a);
                }
            } else {
#pragma unroll
                for (int rg = 0; rg < 4; ++rg) {
                    int mg = m0 + moff + mi * 16 + quad * 4 + rg;
                    if (mg >= M) continue;
                    float v = acc[mi][nj][rg] * s + bb;
                    v = v > 0.f ? v : 0.f;
                    int wq = mg % Wimg;
                    int tq = mg / Wimg;
                    int hq = h0 + tq % HS;
                    int bq = tq / HS;
                    if (MODE == 0) {
                        size_t a = ((size_t)bq * obst + (size_t)(hq - oh0 + oph) * WpOut + (wq + opw)) * N + nglob;
                        split_store(v, Ohi, Olo, a);
                    } else {
                        size_t a = (((size_t)bq * N + nglob) * HS + (hq - h0)) * Wimg + wq;
                        Fo[a] = v;
                    }
                }
            }
        }
}

// ========================= scans + tail (proven) =========================
__global__ __launch_bounds__(256) void repack_scan_k(const float* __restrict__ w, float* __restrict__ wre) {
    int gid = blockIdx.x * 256 + threadIdx.x;
    if (gid >= 128 * 128 * 9) return;
    int o = gid / 1152;
    int r = gid - o * 1152;
    wre[r * 128 + o] = w[gid];
}

__global__ __launch_bounds__(256) void scan_row_k(float* __restrict__ F, const float* __restrict__ wsc, int hp, int hc) {
    __shared__ float sm[128 * 12];
    int b = blockIdx.x / 25;
    int w0 = (blockIdx.x % 25) * 4;
    int tid = threadIdx.x;
    const float* Fp = F + ((size_t)(b * 128) * 36 + hp) * 100;
    for (int i = tid; i < 1536; i += 256) {
        int ci = i / 12;
        int j = i - ci * 12;
        int iw = w0 - 4 + j;
        sm[i] = (iw >= 0 && iw < 100) ? Fp[(size_t)ci * 3600 + iw] : 0.f;
    }
    __syncthreads();
    int o = tid & 127;
    int half = tid >> 7;
    float a0 = 0.f, a1 = 0.f;
    for (int ci = 0; ci < 128; ++ci) {
        const float* s = sm + ci * 12 + half * 2;
        const float* wp = wsc + ci * 9 * 128 + o;
#pragma unroll
        for (int k = 0; k < 9; ++k) {
            float wt = wp[k * 128];
            a0 = fmaf(s[k], wt, a0);
            a1 = fmaf(s[k + 1], wt, a1);
        }
    }
    int w = w0 + half * 2;
    float* outp = F + ((size_t)(b * 128 + o) * 36 + hc) * 100 + w;
    outp[0] += a0 > 0.f ? a0 : 0.f;
    outp[1] += a1 > 0.f ? a1 : 0.f;
}

// column scan on transposed FT [4,128,100,36] (h contiguous): coalesced staging
__global__ __launch_bounds__(256) void scan_colT_k(float* __restrict__ FT, const float* __restrict__ wsc, int wp_, int wc) {
    __shared__ float sm[128 * 12];
    int b = blockIdx.x / 9;
    int h0 = (blockIdx.x % 9) * 4;
    int tid = threadIdx.x;
    const float* Fp = FT + (size_t)(b * 128) * 3600 + (size_t)wp_ * 36;
    for (int i = tid; i < 1536; i += 256) {
        int ci = i / 12;
        int j = i - ci * 12;
        int ih = h0 - 4 + j;
        sm[i] = (ih >= 0 && ih < 36) ? Fp[(size_t)ci * 3600 + ih] : 0.f;
    }
    __syncthreads();
    int o = tid & 127;
    int half = tid >> 7;
    float a0 = 0.f, a1 = 0.f;
    for (int ci = 0; ci < 128; ++ci) {
        const float* s = sm + ci * 12 + half * 2;
        const float* wp = wsc + ci * 9 * 128 + o;
#pragma unroll
        for (int k = 0; k < 9; ++k) {
            float wt = wp[k * 128];
            a0 = fmaf(s[k], wt, a0);
            a1 = fmaf(s[k + 1], wt, a1);
        }
    }
    int h = h0 + half * 2;
    float* outp = FT + ((size_t)(b * 128 + o) * 100 + wc) * 36 + h;
    outp[0] += a0 > 0.f ? a0 : 0.f;
    outp[1] += a1 > 0.f ? a1 : 0.f;
}

// F [4,128,36,100] -> FT [4,128,100,36] (coalesced writes)
__global__ __launch_bounds__(256) void transpose_fwd_k(const float* __restrict__ F, float* __restrict__ FT) {
    int gid = blockIdx.x * 256 + threadIdx.x;
    if (gid >= 4 * 128 * 3600) return;
    int h = gid % 36;
    int t = gid / 36;
    int w = t % 100;
    int bc = t / 100;
    FT[gid] = F[(size_t)bc * 3600 + h * 100 + w];
}
// FT -> F (coalesced writes)
__global__ __launch_bounds__(256) void transpose_bwd_k(const float* __restrict__ FT, float* __restrict__ F) {
    int gid = blockIdx.x * 256 + threadIdx.x;
    if (gid >= 4 * 128 * 3600) return;
    int w = gid % 100;
    int t = gid / 100;
    int h = t % 36;
    int bc = t / 36;
    F[gid] = FT[(size_t)bc * 3600 + w * 36 + h];
}

__global__ __launch_bounds__(256) void conv8_k(const float* __restrict__ F, const float* __restrict__ w8,
                                               const float* __restrict__ b8, float* __restrict__ G) {
    int gid = blockIdx.x * 256 + threadIdx.x;
    if (gid >= NB * 3600) return;
    int hw = gid % 3600;
    int b = gid / 3600;
    float acc[5];
#pragma unroll
    for (int c = 0; c < 5; ++c) acc[c] = b8[c];
    const float* Fb = F + (size_t)b * 128 * 3600 + hw;
    for (int ci = 0; ci < 128; ++ci) {
        float v = Fb[(size_t)ci * 3600];
#pragma unroll
        for (int c = 0; c < 5; ++c) acc[c] = fmaf(v, w8[c * 128 + ci], acc[c]);
    }
#pragma unroll
    for (int c = 0; c < 5; ++c) G[(size_t)(b * 5 + c) * 3600 + hw] = acc[c];
}

__global__ __launch_bounds__(256) void resize_softmax_k(const float* __restrict__ G, float* __restrict__ out) {
    int gid = blockIdx.x * 256 + threadIdx.x;
    if (gid >= NB * 288 * 800) return;
    int ox = gid % 800;
    int t = gid / 800;
    int oy = t % 288;
    int b = t / 288;
    float fy = oy * (35.0f / 287.0f);
    int y0 = (int)fy; if (y0 > 34) y0 = 34;
    int y1 = y0 + 1;
    float wy = fy - y0;
    float fx = ox * (99.0f / 799.0f);
    int x0 = (int)fx; if (x0 > 98) x0 = 98;
    int x1 = x0 + 1;
    float wx = fx - x0;
    const float* Gb = G + (size_t)b * 5 * 3600;
    float v[5];
    float m = -1e30f;
#pragma unroll
    for (int c = 0; c < 5; ++c) {
        const float* Gc = Gb + (size_t)c * 3600;
        float a = Gc[y0 * 100 + x0] * (1.f - wx) + Gc[y0 * 100 + x1] * wx;
        float bb = Gc[y1 * 100 + x0] * (1.f - wx) + Gc[y1 * 100 + x1] * wx;
        v[c] = a * (1.f - wy) + bb * wy;
        m = fmaxf(m, v[c]);
    }
    float sum = 0.f;
#pragma unroll
    for (int c = 0; c < 5; ++c) { v[c] = expf(v[c] - m); sum += v[c]; }
    float inv = 1.f / sum;
#pragma unroll
    for (int c = 0; c < 5; ++c) out[((size_t)(b * 5 + c) * 288 + oy) * 800 + ox] = v[c] * inv;
}

__global__ __launch_bounds__(256) void pool_softmax_k(const float* __restrict__ G, float* __restrict__ P) {
    int gid = blockIdx.x * 256 + threadIdx.x;
    if (gid >= NB * 18 * 50) return;
    int pw = gid % 50;
    int t = gid / 50;
    int ph = t % 18;
    int b = t / 18;
    float s5[5] = {0.f, 0.f, 0.f, 0.f, 0.f};
    const float* Gb = G + (size_t)b * 5 * 3600;
#pragma unroll
    for (int dy = 0; dy < 2; ++dy) {
#pragma unroll
        for (int dx = 0; dx < 2; ++dx) {
            int hw = (2 * ph + dy) * 100 + (2 * pw + dx);
            float v[5], m = -1e30f, sum = 0.f;
#pragma unroll
            for (int c = 0; c < 5; ++c) { v[c] = Gb[(size_t)c * 3600 + hw]; m = fmaxf(m, v[c]); }
#pragma unroll
            for (int c = 0; c < 5; ++c) { v[c] = expf(v[c] - m); sum += v[c]; }
            float inv = 1.f / sum;
#pragma unroll
            for (int c = 0; c < 5; ++c) s5[c] += v[c] * inv;
        }
    }
#pragma unroll
    for (int c = 0; c < 5; ++c) P[b * 4500 + c * 900 + ph * 50 + pw] = s5[c] * 0.25f;
}

__global__ __launch_bounds__(256) void fc1_k(const float* __restrict__ P, const float* __restrict__ fw9,
                                             const float* __restrict__ fb9, float* __restrict__ H1) {
    int wid = blockIdx.x * 4 + (threadIdx.x >> 6);
    int lane = threadIdx.x & 63;
    if (wid >= 512) return;
    int b = wid >> 7;
    int o = wid & 127;
    const float* wr = fw9 + (size_t)o * 4500;
    const float* pr = P + b * 4500;
    float acc = 0.f;
    for (int i = lane; i < 4500; i += 64) acc = fmaf(wr[i], pr[i], acc);
    for (int s = 32; s > 0; s >>= 1) acc += __shfl_down(acc, s, 64);
    if (lane == 0) {
        float r = acc + fb9[o];
        H1[b * 128 + o] = r > 0.f ? r : 0.f;
    }
}

__global__ __launch_bounds__(64) void fc2_k(const float* __restrict__ H1, const float* __restrict__ fw10,
                                            const float* __restrict__ fb10, float* __restrict__ dout) {
    int t = threadIdx.x;
    if (t >= 16) return;
    int b = t >> 2;
    int o = t & 3;
    float acc = fb10[o];
    for (int i = 0; i < 128; ++i) acc = fmaf(H1[b * 128 + i], fw10[o * 128 + i], acc);
    dout[4608000 + t] = 1.f / (1.f + expf(-acc));
}

// ======================================================================================
static inline int ceildiv(int a, int b) { return (a + b - 1) / b; }

extern "C" void kernel_launch(void* const* d_in, const int* in_sizes, int n_in,
                              void* d_out, int out_size, void* d_ws, size_t ws_size,
                              hipStream_t stream) {
    (void)in_sizes; (void)n_in; (void)out_size; (void)ws_size;
    char* U = (char*)d_ws;                 // 19,000,064 B utility region
    char* V = U + 19000064;                // 103,424,000 B activation arena

    // ---- U lifetimes ----
    float* W11f = (float*)(U);                       // 6912 B
    ushort_t* WM12 = (ushort_t*)(U + 8192);          // 9*64*64/plane
    ushort_t* WM21 = (ushort_t*)(U + 155648);        // 9*128*64/plane
    ushort_t* WM22 = (ushort_t*)(U + 450560);        // 9*128*128/plane
    ushort_t* T1hi = (ushort_t*)(U + 1050624);       // [4,20,802,64] 8,212,480 B/plane
    ushort_t* T1lo = (ushort_t*)(U + 1050624 + 8212480);
    ushort_t* T3hi = (ushort_t*)(U + 1050624);       // [4,20,402,128] 8,232,960 B/plane
    ushort_t* T3lo = (ushort_t*)(U + 1050624 + 8232960);
    ushort_t* WMa = (ushort_t*)(U);
    ushort_t* WMb = (ushort_t*)(U + 4718592);
    float* WSC = (float*)(U);
    float* G = (float*)(U + 2359296);
    float* P = (float*)(U + 2647296);
    float* H1 = (float*)(U + 2719296);

    // ---- V lifetimes ----
    ushort_t* Xhi = (ushort_t*)(V);                  // [4,74,202,128] pad(1)
    ushort_t* Xlo = (ushort_t*)(V + 15306752);
    ushort_t* S1hi = (ushort_t*)(V + 30613504);      // [4,146,402,64] pad(1) 30,050,304 B/plane
    ushort_t* S1lo = (ushort_t*)(V + 60663808);
    ushort_t* T2hi = (ushort_t*)(V + 90714112);      // 3,686,400 B/plane
    ushort_t* T2lo = (ushort_t*)(V + 90714112 + 3686400);
    ushort_t* Yhi = (ushort_t*)(V + 30613504);       // conv31 out [4,74,202,256]
    ushort_t* Ylo = (ushort_t*)(V + 61227008);
    ushort_t* Zhi = (ushort_t*)(V + 91840512);       // conv32 strip
    ushort_t* Zlo = (ushort_t*)(V + 97632256);
    ushort_t* HPhi = (ushort_t*)(V);                 // conv33+hpool out [4,72,100,256]
    ushort_t* HPlo = (ushort_t*)(V + 14745600);
    ushort_t* PAhi = (ushort_t*)(V + 30613504);      // pooled stage3 [4,44,108,256] pad(4)
    ushort_t* PAlo = (ushort_t*)(V + 40345600);
    ushort_t* SBhi = (ushort_t*)(V + 50077696);      // 512ch slotB [4,44,108,512]
    ushort_t* SBlo = (ushort_t*)(V + 69541888);
    ushort_t* SAhi = (ushort_t*)(V);                 // 512ch slotA
    ushort_t* SAlo = (ushort_t*)(V + 19464192);
    ushort_t* C6hi = (ushort_t*)(V + 38928384);      // conv6 out [4,36,100,1024]
    ushort_t* C6lo = (ushort_t*)(V + 68419584);
    float* F = (float*)(V);                          // SCNN state fp32 NCHW [0, 7,372,800)
    float* FT = (float*)(V + 7372800);               // transposed state [7.37M, 14.75M)

    const float* X0 = (const float*)d_in[0];
    auto din = [&](int i) { return (const float*)d_in[i]; };
    auto wm_lo = [&](ushort_t* base, int taps, int N, int C) { return base + (size_t)taps * N * C; };

    // ================= stage1 =================
    repack_w_k<<<ceildiv(27 * 64, 256), 256, 0, stream>>>(din(1), W11f, 64, 27);
    repack_wmfma_k<<<ceildiv(64 * 64 * 9, 256), 256, 0, stream>>>(din(4), WM12, wm_lo(WM12, 9, 64, 64), 64, 64, 9);
    hipMemsetAsync(V + 30613504, 0, 60100608, stream);  // S1 padding
    for (int s = 0; s < 16; ++s) {
        int r0 = s * 18;
        conv11_strip_k<<<2005, 256, 0, stream>>>(X0, W11f, din(2), din(3), T1hi, T1lo, r0);
        mfma_conv_k<1, 2><<<dim3(450, 1), 256, 0, stream>>>(
            T1hi, T1lo, WM12, wm_lo(WM12, 9, 64, 64), din(5), din(6), T2hi, T2lo, nullptr,
            57600, 800, 18, r0, 20, 802, 64, r0, 1, 1, 1, 9, 64, 18 * 400, r0, 0, 0, 400);
        vpool2_k<<<ceildiv(4 * 9 * 400 * 64, 256), 256, 0, stream>>>(
            T2hi, T2lo, S1hi, S1lo, 18, 400, 64, 146, 402, 1, r0 / 2);
    }
    // ================= stage2 (NJ=2 regrid: 2x blocks) =================
    repack_wmfma_k<<<ceildiv(128 * 64 * 9, 256), 256, 0, stream>>>(din(7), WM21, wm_lo(WM21, 9, 128, 64), 128, 64, 9);
    repack_wmfma_k<<<ceildiv(128 * 128 * 9, 256), 256, 0, stream>>>(din(10), WM22, wm_lo(WM22, 9, 128, 128), 128, 128, 9);
    hipMemsetAsync(V, 0, 30613504, stream);  // X padding
    for (int s = 0; s < 8; ++s) {
        int r0 = s * 18;
        int hstart = r0 - 1 < 0 ? 0 : r0 - 1;
        int hend = r0 + 19 > 144 ? 144 : r0 + 19;
        int rows = hend - hstart;
        int M21 = 4 * rows * 400;
        hipMemsetAsync(U + 1050624, 0, 16465920, stream);  // T3 both planes
        mfma_conv_k<0, 2><<<dim3(ceildiv(M21, 128), 2), 256, 0, stream>>>(
            S1hi, S1lo, WM21, wm_lo(WM21, 9, 128, 64), din(8), din(9), T3hi, T3lo, nullptr,
            M21, 400, rows, hstart, 146, 402, 64, 0, 1, 1, 1, 9, 128, 20 * 402, r0 - 1, 0, 1, 402);
        mfma_conv_k<1, 2><<<dim3(225, 2), 256, 0, stream>>>(
            T3hi, T3lo, WM22, wm_lo(WM22, 9, 128, 128), din(11), din(12), T2hi, T2lo, nullptr,
            28800, 400, 18, r0, 20, 402, 128, r0 - 1, 0, 1, 1, 9, 128, 18 * 200, r0, 0, 0, 200);
        vpool2_k<<<ceildiv(4 * 9 * 200 * 128, 256), 256, 0, stream>>>(
            T2hi, T2lo, Xhi, Xlo, 18, 200, 128, 74, 202, 1, r0 / 2);
    }

    // ================= conv31 =================
    repack_wmfma_k<<<ceildiv(256 * 128 * 9, 256), 256, 0, stream>>>(din(13), WMa, wm_lo(WMa, 9, 256, 128), 256, 128, 9);
    hipMemsetAsync(V + 30613504, 0, 61227008, stream);
    mfma_conv_k<0, 4><<<dim3(450, 2), 256, 0, stream>>>(
        Xhi, Xlo, WMa, wm_lo(WMa, 9, 256, 128), din(14), din(15), Yhi, Ylo, nullptr,
        57600, 200, 72, 0, 74, 202, 128, 0, 1, 1, 1, 9, 256, 74 * 202, 0, 1, 1, 202);
    // ================= conv32/conv33+hpool strips (NJ=2 regrid) =================
    repack_wmfma_k<<<ceildiv(256 * 256 * 9, 256), 256, 0, stream>>>(din(16), WMa, wm_lo(WMa, 9, 256, 256), 256, 256, 9);
    repack_wmfma_k<<<ceildiv(256 * 256 * 9, 256), 256, 0, stream>>>(din(19), WMb, wm_lo(WMb, 9, 256, 256), 256, 256, 9);
    for (int s = 0; s < 6; ++s) {
        int h0s = s * 12;
        int hstart = h0s - 1 < 0 ? 0 : h0s - 1;
        int hend = h0s + 13 > 72 ? 72 : h0s + 13;
        int rows = hend - hstart;
        int M32 = 4 * rows * 200;
        hipMemsetAsync(V + 91840512, 0, 11583488, stream);
        mfma_conv_k<0, 2><<<dim3(ceildiv(M32, 128), 4), 256, 0, stream>>>(
            Yhi, Ylo, WMa, wm_lo(WMa, 9, 256, 256), din(17), din(18), Zhi, Zlo, nullptr,
            M32, 200, rows, hstart, 74, 202, 256, 0, 1, 1, 1, 9, 256, 14 * 202, h0s - 1, 0, 1, 202);
        mfma_conv_k<1, 2><<<dim3(75, 4), 256, 0, stream>>>(
            Zhi, Zlo, WMb, wm_lo(WMb, 9, 256, 256), din(20), din(21), HPhi, HPlo, nullptr,
            9600, 200, 12, h0s, 14, 202, 256, h0s - 1, 0, 1, 1, 9, 256, 72 * 100, 0, 0, 0, 100);
    }
    hipMemsetAsync(V + 30613504, 0, 19464192, stream);
    vpool2_k<<<ceildiv(4 * 36 * 100 * 256, 256), 256, 0, stream>>>(
        HPhi, HPlo, PAhi, PAlo, 72, 100, 256, 44, 108, 4, 0);

    // ================= conv41..conv53 =================
    struct L { int wi, si, bi, dil; };
    static const L l45[5] = {{25, 26, 27, 1}, {28, 29, 30, 1}, {31, 32, 33, 2}, {34, 35, 36, 2}, {37, 38, 39, 2}};
    repack_wmfma_k<<<ceildiv(512 * 256 * 9, 256), 256, 0, stream>>>(din(22), WMa, wm_lo(WMa, 9, 512, 256), 512, 256, 9);
    hipMemsetAsync(V + 50077696, 0, 38928384, stream);
    mfma_conv_k<0, 4><<<dim3(113, 4), 256, 0, stream>>>(
        PAhi, PAlo, WMa, wm_lo(WMa, 9, 512, 256), din(23), din(24), SBhi, SBlo, nullptr,
        14400, 100, 36, 0, 44, 108, 256, 0, 4, 4, 1, 9, 512, 44 * 108, 0, 4, 4, 108);
    hipMemsetAsync(V, 0, 38928384, stream);  // slotA borders
    for (int i = 0; i < 5; ++i) {
        const L& L0 = l45[i];
        repack_wmfma_k<<<ceildiv(512 * 512 * 9, 256), 256, 0, stream>>>(din(L0.wi), WMa, wm_lo(WMa, 9, 512, 512), 512, 512, 9);
        const ushort_t* ih = (i & 1) ? SAhi : SBhi;
        const ushort_t* il = (i & 1) ? SAlo : SBlo;
        ushort_t* oh = (i & 1) ? SBhi : SAhi;
        ushort_t* ol = (i & 1) ? SBlo : SAlo;
        mfma_conv_k<0, 4><<<dim3(113, 4), 256, 0, stream>>>(
            ih, il, WMa, wm_lo(WMa, 9, 512, 512), din(L0.si), din(L0.bi), oh, ol, nullptr,
            14400, 100, 36, 0, 44, 108, 512, 0, 4, 4, L0.dil, 9, 512, 44 * 108, 0, 4, 4, 108);
    }
    repack_wmfma_k<<<ceildiv(1024 * 512 * 9, 256), 256, 0, stream>>>(din(40), WMa, wm_lo(WMa, 9, 1024, 512), 1024, 512, 9);
    mfma_conv_k<0, 4><<<dim3(113, 8), 256, 0, stream>>>(
        SAhi, SAlo, WMa, wm_lo(WMa, 9, 1024, 512), din(41), din(42), C6hi, C6lo, nullptr,
        14400, 100, 36, 0, 44, 108, 512, 0, 4, 4, 4, 9, 1024, 3600, 0, 0, 0, 100);
    repack_wmfma_k<<<ceildiv(128 * 1024, 256), 256, 0, stream>>>(din(43), WMa, wm_lo(WMa, 1, 128, 1024), 128, 1024, 1);
    mfma_conv_k<2, 4><<<dim3(113, 1), 256, 0, stream>>>(
        C6hi, C6lo, WMa, wm_lo(WMa, 1, 128, 1024), din(44), din(45), nullptr, nullptr, F,
        14400, 100, 36, 0, 36, 100, 1024, 0, 0, 0, 1, 1, 128, 0, 0, 0, 0, 0);

    // ================= SCNN scans + tail =================
    for (int j = 0; j < 4; ++j)
        repack_scan_k<<<576, 256, 0, stream>>>(din(46 + j), WSC + (size_t)j * 147456);
    for (int h = 1; h <= 35; ++h)
        scan_row_k<<<100, 256, 0, stream>>>(F, WSC + 0 * 147456, h - 1, h);
    for (int h = 34; h >= 1; --h)
        scan_row_k<<<100, 256, 0, stream>>>(F, WSC + 1 * 147456, h + 1, h);
    transpose_fwd_k<<<7200, 256, 0, stream>>>(F, FT);
    for (int w = 1; w <= 99; ++w)
        scan_colT_k<<<36, 256, 0, stream>>>(FT, WSC + 2 * (size_t)147456, w - 1, w);
    for (int w = 98; w >= 1; --w)
        scan_colT_k<<<36, 256, 0, stream>>>(FT, WSC + 3 * (size_t)147456, w + 1, w);
    transpose_bwd_k<<<7200, 256, 0, stream>>>(FT, F);

    conv8_k<<<ceildiv(NB * 3600, 256), 256, 0, stream>>>(F, din(50), din(51), G);
    resize_softmax_k<<<ceildiv(NB * 288 * 800, 256), 256, 0, stream>>>(G, (float*)d_out);
    pool_softmax_k<<<ceildiv(NB * 18 * 50, 256), 256, 0, stream>>>(G, P);
    fc1_k<<<128, 256, 0, stream>>>(P, din(52), din(53), H1);
    fc2_k<<<1, 64, 0, stream>>>(H1, din(54), din(55), (float*)d_out);
}